// Round 6
// baseline (3045.434 us; speedup 1.0000x reference)
//
#include <hip/hip_runtime.h>
#include <cstdint>

#define NN 25000
#define NE 300000
#define ECH 150000   // e-FFN chunk rows (Mid fits exactly in sc_bf)

typedef unsigned short ushort_t;
typedef __attribute__((ext_vector_type(8))) short bf16x8;
typedef __attribute__((ext_vector_type(4))) float f32x4;
typedef __attribute__((ext_vector_type(4))) unsigned short u16x4;
typedef __attribute__((ext_vector_type(8))) unsigned short u16x8;

__device__ __forceinline__ float4 ld4(const float* p){ return *reinterpret_cast<const float4*>(p); }
__device__ __forceinline__ void st4(float* p, const float4& v){ *reinterpret_cast<float4*>(p) = v; }
__device__ __forceinline__ float bf2f(ushort_t u){ return __uint_as_float((unsigned)u << 16); }
__device__ __forceinline__ ushort_t f2bfu(float f){
  unsigned x = __float_as_uint(f);
  return (ushort_t)((x + 0x7fffu + ((x >> 16) & 1u)) >> 16);   // RNE
}

// fixed-point (2^32): order-independent integer accumulation -> deterministic
#define FXS 4294967296.0
#define FXI 2.3283064365386963e-10
__device__ __forceinline__ long long f2fx(float v) {
  return (long long)llrint((double)v * FXS);
}
__device__ __forceinline__ float fx2f(long long q) { return (float)((double)q * FXI); }

// ---------- weight convert+transpose: dst[mat][n][k] = bf16(src[mat][k][n]) ----------
__global__ __launch_bounds__(256)
void wconv_k(const float* __restrict__ src, ushort_t* __restrict__ dst,
             int K, int N, int total)
{
  int i = blockIdx.x * 256 + threadIdx.x;
  if (i >= total) return;
  int kn = K * N;
  int mat = i / kn, r = i - mat * kn;
  int n = r / K, k = r - n * K;
  dst[i] = f2bfu(src[(size_t)mat * kn + (size_t)k * N + n]);
}

// ---------- gathers ----------
__global__ __launch_bounds__(256)
void gather_h_k(const float* __restrict__ tab, const int* __restrict__ idx,
                float* __restrict__ hf, ushort_t* __restrict__ hb)
{
  int t = blockIdx.x * 256 + threadIdx.x;
  if (t >= NN * 32) return;
  int i = t >> 5, c4 = t & 31;
  float4 v = ld4(tab + (size_t)idx[i] * 128 + c4 * 4);
  st4(hf + (size_t)i * 128 + c4 * 4, v);
  u16x4 b = { f2bfu(v.x), f2bfu(v.y), f2bfu(v.z), f2bfu(v.w) };
  *reinterpret_cast<u16x4*>(hb + (size_t)i * 128 + c4 * 4) = b;
}

__global__ __launch_bounds__(256)
void gather_e_k(const float* __restrict__ tab, const int* __restrict__ idx,
                ushort_t* __restrict__ eb)
{
  int t = blockIdx.x * 256 + threadIdx.x;
  if (t >= NE * 32) return;
  int i = t >> 5, c4 = t & 31;
  float4 v = ld4(tab + (size_t)idx[i] * 128 + c4 * 4);
  u16x4 b = { f2bfu(v.x), f2bfu(v.y), f2bfu(v.z), f2bfu(v.w) };
  *reinterpret_cast<u16x4*>(eb + (size_t)i * 128 + c4 * 4) = b;
}

// ---------- CSR build (per call; graph shared by all 4 layers) ----------
__global__ __launch_bounds__(256)
void count_k(const int* __restrict__ dst, int* __restrict__ counts)
{
  int e = blockIdx.x * 256 + threadIdx.x;
  if (e < NE) atomicAdd(&counts[dst[e]], 1);
}

__global__ __launch_bounds__(1024)
void scan_k(const int* __restrict__ counts, int* __restrict__ start,
            int* __restrict__ cursor)
{
  __shared__ int part[1024];
  const int t = threadIdx.x;
  const int base = t * 25;                    // 1024*25 = 25600 >= NN
  int loc[25];
  int s = 0;
#pragma unroll
  for (int i = 0; i < 25; ++i) {
    int n = base + i;
    int c = (n < NN) ? counts[n] : 0;
    loc[i] = s; s += c;
  }
  part[t] = s;
  __syncthreads();
  for (int off = 1; off < 1024; off <<= 1) {
    int v = (t >= off) ? part[t - off] : 0;
    __syncthreads();
    part[t] += v;
    __syncthreads();
  }
  int excl = (t == 0) ? 0 : part[t - 1];
#pragma unroll
  for (int i = 0; i < 25; ++i) {
    int n = base + i;
    if (n < NN) { int v = excl + loc[i]; start[n] = v; cursor[n] = v; }
  }
  if (t == 0) start[NN] = NE;
}

__global__ __launch_bounds__(256)
void scatter_k(const int* __restrict__ src, const int* __restrict__ dst,
               int* __restrict__ cursor, int2* __restrict__ csr_es)
{
  int e = blockIdx.x * 256 + threadIdx.x;
  if (e >= NE) return;
  int pos = atomicAdd(&cursor[dst[e]], 1);    // order nondet; reduce is order-indep
  csr_es[pos] = make_int2(e, src[e]);
}

// ---------- generalized MFMA GEMM: [M,K]@[K,N], K in {128,256}, N = gridDim.y*128 ----
// 256 thr = 4 waves; tile 128x128 per block; 70KB LDS -> 2 blocks/CU.
// Epilogues: G!=null -> LN(acc+Bias+Res) (requires gridDim.y==1, ldo==128);
//            relu!=0 -> bf16(relu(acc+Bias)); else plain bf16 store.
// A-frag: lane l holds X[m, kt*32+(l>>4)*8+j], m = base+(l&15)
// B-frag: lane l holds W[kt*32+(l>>4)*8+j, n], n = base+(l&15)  (WT[n][k])
// D: col = l&15, row = (l>>4)*4 + reg   (m89-verified)
__global__ __launch_bounds__(256)
void gemmN_bf_k(const ushort_t* __restrict__ A, const ushort_t* __restrict__ WT,
                const int K, const int M, const int ldo,
                const float* __restrict__ Bias, const int relu,
                const float* __restrict__ ResF, const ushort_t* __restrict__ ResB,
                const float* __restrict__ G, const float* __restrict__ Bb,
                ushort_t* __restrict__ OutB, float* __restrict__ OutF)
{
  __shared__ __align__(16) ushort_t SM[2 * 128 * 136];
  __shared__ float mu[128], rs[128];
  ushort_t* Xs = SM;
  ushort_t* Ws = SM + 128 * 136;
  const int tid = threadIdx.x;
  const int m0 = blockIdx.x * 128;
  const int col0 = blockIdx.y * 128;

  const int l = tid & 63, wv = tid >> 6;
  const int lr = l & 15, lk = l >> 4;
  const int mb = (wv & 1) * 64, nb = (wv >> 1) * 64;
  f32x4 acc[4][4];
  const f32x4 zf = {0.f, 0.f, 0.f, 0.f};
#pragma unroll
  for (int mi = 0; mi < 4; ++mi)
#pragma unroll
    for (int ni = 0; ni < 4; ++ni) acc[mi][ni] = zf;

  for (int kc = 0; kc < K; kc += 128) {
    if (kc) __syncthreads();    // prior-chunk readers done before restage
    for (int c = tid; c < 2048; c += 256) {
      int r = c >> 4, k8 = c & 15;
      bf16x8 v = {};
      if (m0 + r < M)
        v = *reinterpret_cast<const bf16x8*>(A + (size_t)(m0 + r) * K + kc + k8 * 8);
      *reinterpret_cast<bf16x8*>(Xs + r * 136 + k8 * 8) = v;
    }
    for (int c = tid; c < 2048; c += 256) {
      int r = c >> 4, k8 = c & 15;
      *reinterpret_cast<bf16x8*>(Ws + r * 136 + k8 * 8) =
          *reinterpret_cast<const bf16x8*>(WT + (size_t)(col0 + r) * K + kc + k8 * 8);
    }
    __syncthreads();
#pragma unroll
    for (int kt = 0; kt < 4; ++kt) {
      bf16x8 af[4], bw[4];
#pragma unroll
      for (int i = 0; i < 4; ++i)
        af[i] = *reinterpret_cast<const bf16x8*>(Xs + (mb + i * 16 + lr) * 136 + kt * 32 + lk * 8);
#pragma unroll
      for (int i = 0; i < 4; ++i)
        bw[i] = *reinterpret_cast<const bf16x8*>(Ws + (nb + i * 16 + lr) * 136 + kt * 32 + lk * 8);
#pragma unroll
      for (int mi = 0; mi < 4; ++mi)
#pragma unroll
        for (int ni = 0; ni < 4; ++ni)
          acc[mi][ni] = __builtin_amdgcn_mfma_f32_16x16x32_bf16(af[mi], bw[ni], acc[mi][ni], 0, 0, 0);
    }
  }

  if (G == nullptr) {
    if (relu) {   // FFN1: relu(acc + bias) -> bf16
#pragma unroll
      for (int mi = 0; mi < 4; ++mi)
#pragma unroll
        for (int rr = 0; rr < 4; ++rr) {
          int row = m0 + mb + mi * 16 + lk * 4 + rr;
          if (row < M) {
#pragma unroll
            for (int ni = 0; ni < 4; ++ni) {
              int col = nb + ni * 16 + lr;
              OutB[(size_t)row * ldo + col0 + col] =
                  f2bfu(fmaxf(acc[mi][ni][rr] + Bias[col0 + col], 0.f));
            }
          }
        }
    } else {      // plain (QKV / pe)
#pragma unroll
      for (int mi = 0; mi < 4; ++mi)
#pragma unroll
        for (int rr = 0; rr < 4; ++rr) {
          int row = m0 + mb + mi * 16 + lk * 4 + rr;
          if (row < M) {
#pragma unroll
            for (int ni = 0; ni < 4; ++ni)
              OutB[(size_t)row * ldo + col0 + nb + ni * 16 + lr] = f2bfu(acc[mi][ni][rr]);
          }
        }
    }
    return;
  }

  // LN epilogue: T = acc + bias + resid; LN (ldo==128, col0==0)
  __syncthreads();
  float* Tf = reinterpret_cast<float*>(SM);   // [128][132]
#pragma unroll
  for (int mi = 0; mi < 4; ++mi)
#pragma unroll
    for (int rr = 0; rr < 4; ++rr) {
      int row = mb + mi * 16 + lk * 4 + rr;
      int grow = m0 + row;
#pragma unroll
      for (int ni = 0; ni < 4; ++ni) {
        int col = nb + ni * 16 + lr;
        float t = acc[mi][ni][rr] + Bias[col];
        if (grow < M)
          t += ResF ? ResF[(size_t)grow * 128 + col] : bf2f(ResB[(size_t)grow * 128 + col]);
        Tf[row * 132 + col] = t;
      }
    }
  __syncthreads();
  {
    int r = tid >> 1, jj = tid & 1;
    const float* tp = Tf + r * 132 + jj * 64;
    float s = 0.f;
    for (int c2 = 0; c2 < 64; ++c2) s += tp[c2];
    s += __shfl_xor(s, 1);
    float mean = s * (1.f / 128.f);
    float v = 0.f;
    for (int c2 = 0; c2 < 64; ++c2) { float d = tp[c2] - mean; v += d * d; }
    v += __shfl_xor(v, 1);
    if (jj == 0) { mu[r] = mean; rs[r] = 1.f / sqrtf(v * (1.f / 128.f) + 1e-5f); }
  }
  __syncthreads();
  for (int c = tid; c < 4096; c += 256) {
    int r = c >> 5, c4 = c & 31;
    int grow = m0 + r;
    if (grow >= M) continue;
    float4 t = ld4(Tf + r * 132 + c4 * 4);
    float4 gv = ld4(G + c4 * 4), bv = ld4(Bb + c4 * 4);
    float m = mu[r], ir = rs[r];
    float o0 = gv.x * (t.x - m) * ir + bv.x;
    float o1 = gv.y * (t.y - m) * ir + bv.y;
    float o2 = gv.z * (t.z - m) * ir + bv.z;
    float o3 = gv.w * (t.w - m) * ir + bv.w;
    u16x4 ub = { f2bfu(o0), f2bfu(o1), f2bfu(o2), f2bfu(o3) };
    *reinterpret_cast<u16x4*>(OutB + (size_t)grow * 128 + c4 * 4) = ub;
    if (OutF) st4(OutF + (size_t)grow * 128 + c4 * 4, make_float4(o0, o1, o2, o3));
  }
}

// ---------- edge score: sc = K[src]*Q[dst]*0.25*pe (in place), w per head ----------
__global__ __launch_bounds__(256)
void edge_score_k(const ushort_t* __restrict__ Q, const ushort_t* __restrict__ K,
                  ushort_t* __restrict__ PE,
                  const int* __restrict__ src, const int* __restrict__ dst,
                  float* __restrict__ wbuf)
{
  int t = blockIdx.x * 256 + threadIdx.x;
  int e = t >> 4;
  if (e >= NE) return;
  int j = t & 15;
  int s = src[e], d = dst[e];
  u16x8 kv = *reinterpret_cast<const u16x8*>(K + (size_t)s * 128 + j * 8);
  u16x8 qv = *reinterpret_cast<const u16x8*>(Q + (size_t)d * 128 + j * 8);
  u16x8 pv = *reinterpret_cast<const u16x8*>(PE + (size_t)e * 128 + j * 8);
  float hsum = 0.f;
  u16x8 ob;
#pragma unroll
  for (int i = 0; i < 8; ++i) {
    float x = bf2f(kv[i]) * bf2f(qv[i]) * 0.25f * bf2f(pv[i]);
    hsum += x; ob[i] = f2bfu(x);
  }
  *reinterpret_cast<u16x8*>(PE + (size_t)e * 128 + j * 8) = ob;
  hsum += __shfl_xor(hsum, 1);               // pair shares the 16-ch head
  float w = expf(fminf(fmaxf(hsum, -5.f), 5.f));
  if ((j & 1) == 0) wbuf[(size_t)e * 8 + (j >> 1)] = w;
}

// ---------- CSR gather-reduce: h_att[n] = (sum w*V[src]) / (sum w + 1e-6) ----------
__global__ __launch_bounds__(256)
void reduce_k(const ushort_t* __restrict__ V, const float* __restrict__ wbuf,
              const int* __restrict__ start, const int2* __restrict__ csr_es,
              ushort_t* __restrict__ out)
{
  int t = blockIdx.x * 256 + threadIdx.x;
  int n = t >> 4;
  if (n >= NN) return;
  int j = t & 15;
  int p0 = start[n], p1 = start[n + 1];
  long long acc[8] = {};
  long long zacc = 0;
  for (int p = p0; p < p1; ++p) {
    int2 es = csr_es[p];
    float w = wbuf[(size_t)es.x * 8 + (j >> 1)];
    u16x8 vv = *reinterpret_cast<const u16x8*>(V + (size_t)es.y * 128 + j * 8);
    zacc += f2fx(w);
#pragma unroll
    for (int i = 0; i < 8; ++i) acc[i] += f2fx(bf2f(vv[i]) * w);
  }
  float zz = fx2f(zacc) + 1e-6f;
  u16x8 ob;
#pragma unroll
  for (int i = 0; i < 8; ++i) ob[i] = f2bfu(fx2f(acc[i]) / zz);
  *reinterpret_cast<u16x8*>(out + (size_t)n * 128 + j * 8) = ob;
}

// ---------- per-graph mean over 1000 nodes ----------
__global__ __launch_bounds__(256)
void graphmean_k(const float* __restrict__ h, float* __restrict__ hg)
{
  __shared__ float red[256];
  int g = blockIdx.x, tid = threadIdx.x;
  int c = tid & 127, half = tid >> 7;
  float s = 0.f;
  for (int r = half; r < 1000; r += 2) s += h[(size_t)(g * 1000 + r) * 128 + c];
  red[tid] = s;
  __syncthreads();
  if (half == 0) hg[g * 128 + c] = (red[c] + red[c + 128]) / 1000.0f;
}

// ---------- readout MLP: 128 -> 64 -> 32 -> 1 ----------
__global__ __launch_bounds__(256)
void readout_k(const float* __restrict__ hg,
               const float* __restrict__ w0, const float* __restrict__ b0,
               const float* __restrict__ w1, const float* __restrict__ b1,
               const float* __restrict__ w2, const float* __restrict__ b2,
               float* __restrict__ out)
{
  __shared__ float hs[25 * 128];
  __shared__ float t0[25 * 64];
  __shared__ float t1[25 * 32];
  int tid = threadIdx.x;
  for (int i = tid; i < 25 * 128; i += 256) hs[i] = hg[i];
  __syncthreads();
  for (int i = tid; i < 25 * 64; i += 256) {
    int r = i >> 6, c = i & 63;
    float a = b0[c];
    for (int k = 0; k < 128; k++) a += hs[r * 128 + k] * w0[k * 64 + c];
    t0[i] = fmaxf(a, 0.f);
  }
  __syncthreads();
  for (int i = tid; i < 25 * 32; i += 256) {
    int r = i >> 5, c = i & 31;
    float a = b1[c];
    for (int k = 0; k < 64; k++) a += t0[r * 64 + k] * w1[k * 32 + c];
    t1[i] = fmaxf(a, 0.f);
  }
  __syncthreads();
  if (tid < 25) {
    float a = b2[0];
    for (int k = 0; k < 32; k++) a += t1[tid * 32 + k] * w2[k];
    out[tid] = a;
  }
}

extern "C" void kernel_launch(void* const* d_in, const int* in_sizes, int n_in,
                              void* d_out, int out_size, void* d_ws, size_t ws_size,
                              hipStream_t stream)
{
  const float* emb_h  = (const float*)d_in[0];
  const float* emb_e  = (const float*)d_in[1];
  const float* w_qkve = (const float*)d_in[2];
  const float* o_w    = (const float*)d_in[3];
  const float* o_b    = (const float*)d_in[4];
  const float* ln_s   = (const float*)d_in[5];
  const float* ln_b   = (const float*)d_in[6];
  const float* ffn_w1 = (const float*)d_in[7];
  const float* ffn_b1 = (const float*)d_in[8];
  const float* ffn_w2 = (const float*)d_in[9];
  const float* ffn_b2 = (const float*)d_in[10];
  const float* mlp_w0 = (const float*)d_in[11];
  const float* mlp_b0 = (const float*)d_in[12];
  const float* mlp_w1 = (const float*)d_in[13];
  const float* mlp_b1 = (const float*)d_in[14];
  const float* mlp_w2 = (const float*)d_in[15];
  const float* mlp_b2 = (const float*)d_in[16];
  const int* tokens = (const int*)d_in[17];
  const int* etype  = (const int*)d_in[18];
  const int* src    = (const int*)d_in[19];
  const int* dst    = (const int*)d_in[20];

  // ---- workspace (~219 MB; <= 237 MB known-good) ----
  char* ws = (char*)d_ws;
  size_t off = 0;
  auto alloc = [&](size_t bytes) { char* p = ws + off; off += bytes; return p; };
  int2*      csr_es = (int2*)alloc((size_t)NE * 8);             // 2.4 MB (8B align first)
  float*     h      = (float*)alloc((size_t)NN * 128 * 4);      // 12.8 MB
  float*     hg     = (float*)alloc(25 * 128 * 4);
  float*     wbuf   = (float*)alloc((size_t)NE * 8 * 4);        // 9.6 MB
  int*       counts = (int*)alloc((size_t)NN * 4);
  int*       cursor = (int*)alloc((size_t)NN * 4);
  int*       startp = (int*)alloc((size_t)(NN + 1) * 4);
  ushort_t*  h_bf   = (ushort_t*)alloc((size_t)NN * 128 * 2);   // 6.4 MB
  ushort_t*  ha_bf  = (ushort_t*)alloc((size_t)NN * 128 * 2);
  ushort_t*  Qb     = (ushort_t*)alloc((size_t)NN * 128 * 2);   // Qb+Kb double as h-FFN Mid
  ushort_t*  Kb     = (ushort_t*)alloc((size_t)NN * 128 * 2);
  ushort_t*  Vb     = (ushort_t*)alloc((size_t)NN * 128 * 2);
  ushort_t*  e_bf   = (ushort_t*)alloc((size_t)NE * 128 * 2);   // 76.8 MB
  ushort_t*  sc_bf  = (ushort_t*)alloc((size_t)NE * 128 * 2);   // 76.8 MB; doubles as e-FFN Mid
  ushort_t*  wt     = (ushort_t*)alloc(917504 * 2);             // 1.84 MB

  // packed transposed bf16 weights
  ushort_t* qkveT = wt;            // 16 mats [128][128]
  ushort_t* owT   = wt + 262144;   // 8 mats  [128][128]
  ushort_t* w1T   = wt + 393216;   // 8 mats  [256][128]
  ushort_t* w2T   = wt + 655360;   // 8 mats  [128][256]
  wconv_k<<<1024, 256, 0, stream>>>(w_qkve, qkveT, 128, 128, 262144);
  wconv_k<<<512,  256, 0, stream>>>(o_w,    owT,   128, 128, 131072);
  wconv_k<<<1024, 256, 0, stream>>>(ffn_w1, w1T,   128, 256, 262144);
  wconv_k<<<1024, 256, 0, stream>>>(ffn_w2, w2T,   256, 128, 262144);

  gather_h_k<<<3125, 256, 0, stream>>>(emb_h, tokens, h, h_bf);
  gather_e_k<<<37500, 256, 0, stream>>>(emb_e, etype, e_bf);

  // CSR by dst (shared across layers)
  hipMemsetAsync(counts, 0, (size_t)NN * 4, stream);
  count_k<<<(NE + 255) / 256, 256, 0, stream>>>(dst, counts);
  scan_k<<<1, 1024, 0, stream>>>(counts, startp, cursor);
  scatter_k<<<(NE + 255) / 256, 256, 0, stream>>>(src, dst, cursor, csr_es);

  const int GN = (NN + 127) / 128;    // 196
  const int GE = (NE + 127) / 128;    // 2344
  const int GC = (ECH + 127) / 128;   // 1172
  ushort_t* MidH = Qb;                // 25000x256 bf16 spans Qb..Kb (12.8 MB)

  for (int l = 0; l < 4; ++l) {
    const ushort_t* wqT  = qkveT + ((size_t)l * 4 + 0) * 16384;
    const ushort_t* wkT  = qkveT + ((size_t)l * 4 + 1) * 16384;
    const ushort_t* wvT  = qkveT + ((size_t)l * 4 + 2) * 16384;
    const ushort_t* weT  = qkveT + ((size_t)l * 4 + 3) * 16384;
    const ushort_t* ow0T = owT + ((size_t)l * 2 + 0) * 16384;
    const ushort_t* ow1T = owT + ((size_t)l * 2 + 1) * 16384;
    const ushort_t* w1hT = w1T + ((size_t)l * 2 + 0) * 32768;
    const ushort_t* w1eT = w1T + ((size_t)l * 2 + 1) * 32768;
    const ushort_t* w2hT = w2T + ((size_t)l * 2 + 0) * 32768;
    const ushort_t* w2eT = w2T + ((size_t)l * 2 + 1) * 32768;
    const float* ob0 = o_b + ((size_t)l * 2 + 0) * 128;
    const float* ob1 = o_b + ((size_t)l * 2 + 1) * 128;
    const float* ls0 = ln_s + ((size_t)l * 4 + 0) * 128;
    const float* ls1 = ln_s + ((size_t)l * 4 + 1) * 128;
    const float* ls2 = ln_s + ((size_t)l * 4 + 2) * 128;
    const float* ls3 = ln_s + ((size_t)l * 4 + 3) * 128;
    const float* lb0 = ln_b + ((size_t)l * 4 + 0) * 128;
    const float* lb1 = ln_b + ((size_t)l * 4 + 1) * 128;
    const float* lb2 = ln_b + ((size_t)l * 4 + 2) * 128;
    const float* lb3 = ln_b + ((size_t)l * 4 + 3) * 128;
    const float* fb1h = ffn_b1 + ((size_t)l * 2 + 0) * 256;
    const float* fb1e = ffn_b1 + ((size_t)l * 2 + 1) * 256;
    const float* fb2h = ffn_b2 + ((size_t)l * 2 + 0) * 128;
    const float* fb2e = ffn_b2 + ((size_t)l * 2 + 1) * 128;

    // QKV + pe projections (plain)
    gemmN_bf_k<<<dim3(GN, 1), 256, 0, stream>>>(h_bf, wqT, 128, NN, 128,
        nullptr, 0, nullptr, nullptr, nullptr, nullptr, Qb, nullptr);
    gemmN_bf_k<<<dim3(GN, 1), 256, 0, stream>>>(h_bf, wkT, 128, NN, 128,
        nullptr, 0, nullptr, nullptr, nullptr, nullptr, Kb, nullptr);
    gemmN_bf_k<<<dim3(GN, 1), 256, 0, stream>>>(h_bf, wvT, 128, NN, 128,
        nullptr, 0, nullptr, nullptr, nullptr, nullptr, Vb, nullptr);
    gemmN_bf_k<<<dim3(GE, 1), 256, 0, stream>>>(e_bf, weT, 128, NE, 128,
        nullptr, 0, nullptr, nullptr, nullptr, nullptr, sc_bf, nullptr);

    edge_score_k<<<18750, 256, 0, stream>>>(Qb, Kb, sc_bf, src, dst, wbuf);
    reduce_k<<<1563, 256, 0, stream>>>(Vb, wbuf, startp, csr_es, ha_bf);

    // h = LN(h + h_att@O_h + b); dual write fp32+bf16
    gemmN_bf_k<<<dim3(GN, 1), 256, 0, stream>>>(ha_bf, ow0T, 128, NN, 128,
        ob0, 0, h, nullptr, ls0, lb0, h_bf, h);
    // e = LN(e + e_att@O_e + b)   (sc_bf dead after this)
    gemmN_bf_k<<<dim3(GE, 1), 256, 0, stream>>>(sc_bf, ow1T, 128, NE, 128,
        ob1, 0, nullptr, e_bf, ls1, lb1, e_bf, nullptr);

    // h-FFN: Mid = relu(h1@W1+b1) -> MidH(Qb..Kb); h = LN(h1 + Mid@W2+b2)
    gemmN_bf_k<<<dim3(GN, 2), 256, 0, stream>>>(h_bf, w1hT, 128, NN, 256,
        fb1h, 1, nullptr, nullptr, nullptr, nullptr, MidH, nullptr);
    gemmN_bf_k<<<dim3(GN, 1), 256, 0, stream>>>(MidH, w2hT, 256, NN, 128,
        fb2h, 0, h, nullptr, ls2, lb2, h_bf, h);

    // e-FFN in 2 chunks of 150000 rows; Mid reuses sc_bf (exactly 76.8 MB)
    for (int c = 0; c < 2; ++c) {
      ushort_t* ec = e_bf + (size_t)c * ECH * 128;
      gemmN_bf_k<<<dim3(GC, 2), 256, 0, stream>>>(ec, w1eT, 128, ECH, 256,
          fb1e, 1, nullptr, nullptr, nullptr, nullptr, sc_bf, nullptr);
      gemmN_bf_k<<<dim3(GC, 1), 256, 0, stream>>>(sc_bf, w2eT, 256, ECH, 128,
          fb2e, 0, nullptr, ec, ls3, lb3, ec, nullptr);
    }
  }

  graphmean_k<<<25, 256, 0, stream>>>(h, hg);
  readout_k<<<1, 256, 0, stream>>>(hg, mlp_w0, mlp_b0, mlp_w1, mlp_b1, mlp_w2, mlp_b2,
                                   (float*)d_out);
}

// Round 7
// 2254.135 us; speedup vs baseline: 1.3510x; 1.3510x over previous
//
#include <hip/hip_runtime.h>
#include <cstdint>

#define NN 25000
#define NE 300000

typedef unsigned short ushort_t;
typedef __attribute__((ext_vector_type(8))) short bf16x8;
typedef __attribute__((ext_vector_type(4))) float f32x4;
typedef __attribute__((ext_vector_type(4))) unsigned short u16x4;
typedef __attribute__((ext_vector_type(8))) unsigned short u16x8;

__device__ __forceinline__ float4 ld4(const float* p){ return *reinterpret_cast<const float4*>(p); }
__device__ __forceinline__ void st4(float* p, const float4& v){ *reinterpret_cast<float4*>(p) = v; }
__device__ __forceinline__ float bf2f(ushort_t u){ return __uint_as_float((unsigned)u << 16); }
__device__ __forceinline__ ushort_t f2bfu(float f){
  unsigned x = __float_as_uint(f);
  return (ushort_t)((x + 0x7fffu + ((x >> 16) & 1u)) >> 16);   // RNE
}

// fixed-point (2^32): order-independent integer accumulation -> deterministic
#define FXS 4294967296.0
#define FXI 2.3283064365386963e-10
__device__ __forceinline__ long long f2fx(float v) {
  return (long long)llrint((double)v * FXS);
}
__device__ __forceinline__ float fx2f(long long q) { return (float)((double)q * FXI); }

#define MFMA(a, b, c) __builtin_amdgcn_mfma_f32_16x16x32_bf16((a), (b), (c), 0, 0, 0)

// ---------- weight convert+transpose: dst[mat][n][k] = bf16(src[mat][k][n]) ----------
__global__ __launch_bounds__(256)
void wconv_k(const float* __restrict__ src, ushort_t* __restrict__ dst,
             int K, int N, int total)
{
  int i = blockIdx.x * 256 + threadIdx.x;
  if (i >= total) return;
  int kn = K * N;
  int mat = i / kn, r = i - mat * kn;
  int n = r / K, k = r - n * K;
  dst[i] = f2bfu(src[(size_t)mat * kn + (size_t)k * N + n]);
}

// ---------- gathers ----------
__global__ __launch_bounds__(256)
void gather_h_k(const float* __restrict__ tab, const int* __restrict__ idx,
                float* __restrict__ hf, ushort_t* __restrict__ hb)
{
  int t = blockIdx.x * 256 + threadIdx.x;
  if (t >= NN * 32) return;
  int i = t >> 5, c4 = t & 31;
  float4 v = ld4(tab + (size_t)idx[i] * 128 + c4 * 4);
  st4(hf + (size_t)i * 128 + c4 * 4, v);
  u16x4 b = { f2bfu(v.x), f2bfu(v.y), f2bfu(v.z), f2bfu(v.w) };
  *reinterpret_cast<u16x4*>(hb + (size_t)i * 128 + c4 * 4) = b;
}

__global__ __launch_bounds__(256)
void gather_e_k(const float* __restrict__ tab, const int* __restrict__ idx,
                ushort_t* __restrict__ eb)
{
  int t = blockIdx.x * 256 + threadIdx.x;
  if (t >= NE * 32) return;
  int i = t >> 5, c4 = t & 31;
  float4 v = ld4(tab + (size_t)idx[i] * 128 + c4 * 4);
  u16x4 b = { f2bfu(v.x), f2bfu(v.y), f2bfu(v.z), f2bfu(v.w) };
  *reinterpret_cast<u16x4*>(eb + (size_t)i * 128 + c4 * 4) = b;
}

// ---------- CSR build (per call; graph shared by all 4 layers) ----------
__global__ __launch_bounds__(256)
void count_k(const int* __restrict__ dst, int* __restrict__ counts)
{
  int e = blockIdx.x * 256 + threadIdx.x;
  if (e < NE) atomicAdd(&counts[dst[e]], 1);
}

__global__ __launch_bounds__(1024)
void scan_k(const int* __restrict__ counts, int* __restrict__ start,
            int* __restrict__ cursor)
{
  __shared__ int part[1024];
  const int t = threadIdx.x;
  const int base = t * 25;
  int loc[25];
  int s = 0;
#pragma unroll
  for (int i = 0; i < 25; ++i) {
    int n = base + i;
    int c = (n < NN) ? counts[n] : 0;
    loc[i] = s; s += c;
  }
  part[t] = s;
  __syncthreads();
  for (int off = 1; off < 1024; off <<= 1) {
    int v = (t >= off) ? part[t - off] : 0;
    __syncthreads();
    part[t] += v;
    __syncthreads();
  }
  int excl = (t == 0) ? 0 : part[t - 1];
#pragma unroll
  for (int i = 0; i < 25; ++i) {
    int n = base + i;
    if (n < NN) { int v = excl + loc[i]; start[n] = v; cursor[n] = v; }
  }
  if (t == 0) start[NN] = NE;
}

__global__ __launch_bounds__(256)
void scatter_k(const int* __restrict__ src, const int* __restrict__ dst,
               int* __restrict__ cursor, int2* __restrict__ csr_es)
{
  int e = blockIdx.x * 256 + threadIdx.x;
  if (e >= NE) return;
  int pos = atomicAdd(&cursor[dst[e]], 1);    // order nondet; reduce is order-indep
  csr_es[pos] = make_int2(e, src[e]);
}

// ---------- MFMA GEMM: [M,K]@[K,N]; coalesced repack stores; opt bias+resid+LN ----
// 256 thr = 4 waves; tile 128x128; 70KB LDS -> 2 blocks/CU.
// osep: blockIdx.y selects weight mat (rows col0..col0+127 of WT) AND output
//       buffer base OutB + y*M*128 (QKV fusion); stores use local cols.
__global__ __launch_bounds__(256)
void gemmN_bf_k(const ushort_t* __restrict__ A, const ushort_t* __restrict__ WT,
                const int K, const int M, const int ldo,
                const float* __restrict__ Bias, const int osep,
                const float* __restrict__ ResF, const ushort_t* __restrict__ ResB,
                const float* __restrict__ G, const float* __restrict__ Bb,
                ushort_t* __restrict__ OutB, float* __restrict__ OutF)
{
  __shared__ __align__(16) ushort_t SM[2 * 128 * 136];
  __shared__ float mu[128], rs[128];
  ushort_t* Xs = SM;
  ushort_t* Ws = SM + 128 * 136;
  const int tid = threadIdx.x;
  const int m0 = blockIdx.x * 128;
  const int col0 = blockIdx.y * 128;

  const int l = tid & 63, wv = tid >> 6;
  const int lr = l & 15, lk = l >> 4;
  const int mb = (wv & 1) * 64, nb = (wv >> 1) * 64;
  f32x4 acc[4][4];
  const f32x4 zf = {0.f, 0.f, 0.f, 0.f};
#pragma unroll
  for (int mi = 0; mi < 4; ++mi)
#pragma unroll
    for (int ni = 0; ni < 4; ++ni) acc[mi][ni] = zf;

  for (int kc = 0; kc < K; kc += 128) {
    if (kc) __syncthreads();
    for (int c = tid; c < 2048; c += 256) {
      int r = c >> 4, k8 = c & 15;
      bf16x8 v = {};
      if (m0 + r < M)
        v = *reinterpret_cast<const bf16x8*>(A + (size_t)(m0 + r) * K + kc + k8 * 8);
      *reinterpret_cast<bf16x8*>(Xs + r * 136 + k8 * 8) = v;
    }
    for (int c = tid; c < 2048; c += 256) {
      int r = c >> 4, k8 = c & 15;
      *reinterpret_cast<bf16x8*>(Ws + r * 136 + k8 * 8) =
          *reinterpret_cast<const bf16x8*>(WT + (size_t)(col0 + r) * K + kc + k8 * 8);
    }
    __syncthreads();
#pragma unroll
    for (int kt = 0; kt < 4; ++kt) {
      bf16x8 af[4], bw[4];
#pragma unroll
      for (int i = 0; i < 4; ++i)
        af[i] = *reinterpret_cast<const bf16x8*>(Xs + (mb + i * 16 + lr) * 136 + kt * 32 + lk * 8);
#pragma unroll
      for (int i = 0; i < 4; ++i)
        bw[i] = *reinterpret_cast<const bf16x8*>(Ws + (nb + i * 16 + lr) * 136 + kt * 32 + lk * 8);
#pragma unroll
      for (int mi = 0; mi < 4; ++mi)
#pragma unroll
        for (int ni = 0; ni < 4; ++ni)
          acc[mi][ni] = MFMA(af[mi], bw[ni], acc[mi][ni]);
    }
  }

  if (G == nullptr) {
    // repack tile to LDS -> coalesced u16x8 stores
    __syncthreads();
    ushort_t* Rb = SM;   // [128][136]
#pragma unroll
    for (int mi = 0; mi < 4; ++mi)
#pragma unroll
      for (int rr = 0; rr < 4; ++rr) {
        int row = mb + mi * 16 + lk * 4 + rr;
#pragma unroll
        for (int ni = 0; ni < 4; ++ni) {
          int col = nb + ni * 16 + lr;
          float v = acc[mi][ni][rr];
          if (Bias) v = fmaxf(v + Bias[col0 + col], 0.f);
          Rb[row * 136 + col] = f2bfu(v);
        }
      }
    __syncthreads();
    ushort_t* ob = OutB + (osep ? (size_t)blockIdx.y * M * 128 : (size_t)col0);
    for (int c = tid; c < 2048; c += 256) {
      int r = c >> 4, k8 = c & 15;
      if (m0 + r < M)
        *reinterpret_cast<u16x8*>(ob + (size_t)(m0 + r) * ldo + k8 * 8) =
            *reinterpret_cast<u16x8*>(Rb + r * 136 + k8 * 8);
    }
    return;
  }

  // LN epilogue: T = acc + bias + resid; LN (ldo==128, col0==0)
  __syncthreads();
  float* Tf = reinterpret_cast<float*>(SM);   // [128][132]
#pragma unroll
  for (int mi = 0; mi < 4; ++mi)
#pragma unroll
    for (int rr = 0; rr < 4; ++rr) {
      int row = mb + mi * 16 + lk * 4 + rr;
      int grow = m0 + row;
#pragma unroll
      for (int ni = 0; ni < 4; ++ni) {
        int col = nb + ni * 16 + lr;
        float t = acc[mi][ni][rr] + Bias[col];
        if (grow < M)
          t += ResF ? ResF[(size_t)grow * 128 + col] : bf2f(ResB[(size_t)grow * 128 + col]);
        Tf[row * 132 + col] = t;
      }
    }
  __syncthreads();
  {
    int r = tid >> 1, jj = tid & 1;
    const float* tp = Tf + r * 132 + jj * 64;
    float s = 0.f;
    for (int c2 = 0; c2 < 64; ++c2) s += tp[c2];
    s += __shfl_xor(s, 1);
    float mean = s * (1.f / 128.f);
    float v = 0.f;
    for (int c2 = 0; c2 < 64; ++c2) { float d = tp[c2] - mean; v += d * d; }
    v += __shfl_xor(v, 1);
    if (jj == 0) { mu[r] = mean; rs[r] = 1.f / sqrtf(v * (1.f / 128.f) + 1e-5f); }
  }
  __syncthreads();
  for (int c = tid; c < 4096; c += 256) {
    int r = c >> 5, c4 = c & 31;
    int grow = m0 + r;
    if (grow >= M) continue;
    float4 t = ld4(Tf + r * 132 + c4 * 4);
    float4 gv = ld4(G + c4 * 4), bv = ld4(Bb + c4 * 4);
    float m = mu[r], ir = rs[r];
    float o0 = gv.x * (t.x - m) * ir + bv.x;
    float o1 = gv.y * (t.y - m) * ir + bv.y;
    float o2 = gv.z * (t.z - m) * ir + bv.z;
    float o3 = gv.w * (t.w - m) * ir + bv.w;
    u16x4 ub = { f2bfu(o0), f2bfu(o1), f2bfu(o2), f2bfu(o3) };
    *reinterpret_cast<u16x4*>(OutB + (size_t)grow * 128 + c4 * 4) = ub;
    if (OutF) st4(OutF + (size_t)grow * 128 + c4 * 4, make_float4(o0, o1, o2, o3));
  }
}

// ---------- fused FFN: out = LN(x + relu(x@W1+b1)@W2+b2) ----------
// 64 rows/block, 256 thr = 4 waves (wave = rows wv*16..wv*16+15), ~70KB LDS.
// Mid kept entirely in LDS: Mid0 = cols 0..127, Mid1 (overwrites Xs) = cols 128..255.
// Weight staged in 4 sequential 34.8KB phases. Residual: ResF (fp32 global, h path)
// or Xs saved to registers pre-overwrite (e path; bit-identical to bf16 input).
__global__ __launch_bounds__(256)
void ffn_f_k(const ushort_t* __restrict__ Xbf, const float* __restrict__ ResF,
             const ushort_t* __restrict__ W1T, const float* __restrict__ B1,
             const ushort_t* __restrict__ W2T, const float* __restrict__ B2,
             const float* __restrict__ G, const float* __restrict__ Bb,
             ushort_t* __restrict__ OutB, float* __restrict__ OutF, int M)
{
  __shared__ __align__(16) ushort_t SM[8704 + 8704 + 17408];
  __shared__ float mu[64], rs[64];
  ushort_t* Xs   = SM;            // [64][136]; becomes Mid1
  ushort_t* Mid0 = SM + 8704;     // [64][136]
  ushort_t* Wst  = SM + 17408;    // [128][136]; becomes Tf f32 [64][132]
  const int tid = threadIdx.x;
  const int m0 = blockIdx.x * 64;
  const int l = tid & 63, wv = tid >> 6, lr = l & 15, lk = l >> 4;
  const f32x4 zf = {0.f, 0.f, 0.f, 0.f};

  // stage Xs + W1a
  for (int c = tid; c < 1024; c += 256) {
    int r = c >> 4, k8 = c & 15;
    bf16x8 v = {};
    if (m0 + r < M) v = *reinterpret_cast<const bf16x8*>(Xbf + (size_t)(m0 + r) * 128 + k8 * 8);
    *reinterpret_cast<bf16x8*>(Xs + r * 136 + k8 * 8) = v;
  }
  for (int c = tid; c < 2048; c += 256) {
    int r = c >> 4, k8 = c & 15;
    *reinterpret_cast<bf16x8*>(Wst + r * 136 + k8 * 8) =
        *reinterpret_cast<const bf16x8*>(W1T + (size_t)r * 128 + k8 * 8);
  }
  __syncthreads();

  f32x4 acc2[8];
#pragma unroll
  for (int i = 0; i < 8; ++i) acc2[i] = zf;
  ushort_t rsv[8][4];

  // FFN1a: Mid0 = relu(X @ W1[:,0:128] + b1[0:128])
  {
    f32x4 a1[8];
#pragma unroll
    for (int i = 0; i < 8; ++i) a1[i] = zf;
#pragma unroll
    for (int kt = 0; kt < 4; ++kt) {
      bf16x8 af = *reinterpret_cast<const bf16x8*>(Xs + (wv * 16 + lr) * 136 + kt * 32 + lk * 8);
#pragma unroll
      for (int ni = 0; ni < 8; ++ni) {
        bf16x8 bw = *reinterpret_cast<const bf16x8*>(Wst + (ni * 16 + lr) * 136 + kt * 32 + lk * 8);
        a1[ni] = MFMA(af, bw, a1[ni]);
      }
    }
#pragma unroll
    for (int ni = 0; ni < 8; ++ni)
#pragma unroll
      for (int rr = 0; rr < 4; ++rr)
        Mid0[(wv * 16 + lk * 4 + rr) * 136 + ni * 16 + lr] =
            f2bfu(fmaxf(a1[ni][rr] + B1[ni * 16 + lr], 0.f));
  }
  __syncthreads();
  // stage W1b
  for (int c = tid; c < 2048; c += 256) {
    int r = c >> 4, k8 = c & 15;
    *reinterpret_cast<bf16x8*>(Wst + r * 136 + k8 * 8) =
        *reinterpret_cast<const bf16x8*>(W1T + (size_t)(128 + r) * 128 + k8 * 8);
  }
  __syncthreads();
  // FFN1b -> save resid from Xs -> Mid1 overwrites Xs
  {
    f32x4 a1[8];
#pragma unroll
    for (int i = 0; i < 8; ++i) a1[i] = zf;
#pragma unroll
    for (int kt = 0; kt < 4; ++kt) {
      bf16x8 af = *reinterpret_cast<const bf16x8*>(Xs + (wv * 16 + lr) * 136 + kt * 32 + lk * 8);
#pragma unroll
      for (int ni = 0; ni < 8; ++ni) {
        bf16x8 bw = *reinterpret_cast<const bf16x8*>(Wst + (ni * 16 + lr) * 136 + kt * 32 + lk * 8);
        a1[ni] = MFMA(af, bw, a1[ni]);
      }
    }
    __syncthreads();   // all waves done reading Xs (and Wst)
    if (!ResF) {       // e path: residual = bf16 input (exactly what Xs holds)
#pragma unroll
      for (int ni = 0; ni < 8; ++ni)
#pragma unroll
        for (int rr = 0; rr < 4; ++rr)
          rsv[ni][rr] = Xs[(wv * 16 + lk * 4 + rr) * 136 + ni * 16 + lr];
    }
    // same-thread read->write (identical lane mapping), no cross-thread hazard
#pragma unroll
    for (int ni = 0; ni < 8; ++ni)
#pragma unroll
      for (int rr = 0; rr < 4; ++rr)
        Xs[(wv * 16 + lk * 4 + rr) * 136 + ni * 16 + lr] =
            f2bfu(fmaxf(a1[ni][rr] + B1[128 + ni * 16 + lr], 0.f));
  }
  __syncthreads();
  // stage W2a (k 0..127)
  for (int c = tid; c < 2048; c += 256) {
    int r = c >> 4, k8 = c & 15;
    *reinterpret_cast<bf16x8*>(Wst + r * 136 + k8 * 8) =
        *reinterpret_cast<const bf16x8*>(W2T + (size_t)r * 256 + k8 * 8);
  }
  __syncthreads();
  // FFN2a: acc2 += Mid0 @ W2[0:128,:]
#pragma unroll
  for (int kt = 0; kt < 4; ++kt) {
    bf16x8 af = *reinterpret_cast<const bf16x8*>(Mid0 + (wv * 16 + lr) * 136 + kt * 32 + lk * 8);
#pragma unroll
    for (int ni = 0; ni < 8; ++ni) {
      bf16x8 bw = *reinterpret_cast<const bf16x8*>(Wst + (ni * 16 + lr) * 136 + kt * 32 + lk * 8);
      acc2[ni] = MFMA(af, bw, acc2[ni]);
    }
  }
  __syncthreads();
  // stage W2b (k 128..255)
  for (int c = tid; c < 2048; c += 256) {
    int r = c >> 4, k8 = c & 15;
    *reinterpret_cast<bf16x8*>(Wst + r * 136 + k8 * 8) =
        *reinterpret_cast<const bf16x8*>(W2T + (size_t)r * 256 + 128 + k8 * 8);
  }
  __syncthreads();
  // FFN2b: acc2 += Mid1 @ W2[128:256,:]
#pragma unroll
  for (int kt = 0; kt < 4; ++kt) {
    bf16x8 af = *reinterpret_cast<const bf16x8*>(Xs + (wv * 16 + lr) * 136 + kt * 32 + lk * 8);
#pragma unroll
    for (int ni = 0; ni < 8; ++ni) {
      bf16x8 bw = *reinterpret_cast<const bf16x8*>(Wst + (ni * 16 + lr) * 136 + kt * 32 + lk * 8);
      acc2[ni] = MFMA(af, bw, acc2[ni]);
    }
  }
  __syncthreads();   // Wst reads done -> reuse as Tf
  float* Tf = reinterpret_cast<float*>(Wst);   // [64][132]
#pragma unroll
  for (int ni = 0; ni < 8; ++ni)
#pragma unroll
    for (int rr = 0; rr < 4; ++rr) {
      int row = wv * 16 + lk * 4 + rr;
      int grow = m0 + row;
      int col = ni * 16 + lr;
      float t = acc2[ni][rr] + B2[col];
      if (ResF) { if (grow < M) t += ResF[(size_t)grow * 128 + col]; }
      else      t += bf2f(rsv[ni][rr]);
      Tf[row * 132 + col] = t;
    }
  __syncthreads();
  {
    int r = tid >> 2, jj = tid & 3;
    const float* tp = Tf + r * 132 + jj * 32;
    float s = 0.f;
    for (int c2 = 0; c2 < 32; ++c2) s += tp[c2];
    s += __shfl_xor(s, 1); s += __shfl_xor(s, 2);
    float mean = s * (1.f / 128.f);
    float v = 0.f;
    for (int c2 = 0; c2 < 32; ++c2) { float d = tp[c2] - mean; v += d * d; }
    v += __shfl_xor(v, 1); v += __shfl_xor(v, 2);
    if (jj == 0) { mu[r] = mean; rs[r] = 1.f / sqrtf(v * (1.f / 128.f) + 1e-5f); }
  }
  __syncthreads();
  for (int c = tid; c < 2048; c += 256) {
    int r = c >> 5, c4 = c & 31;
    int grow = m0 + r;
    if (grow >= M) continue;
    float4 t = ld4(Tf + r * 132 + c4 * 4);
    float4 gv = ld4(G + c4 * 4), bv = ld4(Bb + c4 * 4);
    float m = mu[r], ir = rs[r];
    float o0 = gv.x * (t.x - m) * ir + bv.x;
    float o1 = gv.y * (t.y - m) * ir + bv.y;
    float o2 = gv.z * (t.z - m) * ir + bv.z;
    float o3 = gv.w * (t.w - m) * ir + bv.w;
    u16x4 ub = { f2bfu(o0), f2bfu(o1), f2bfu(o2), f2bfu(o3) };
    *reinterpret_cast<u16x4*>(OutB + (size_t)grow * 128 + c4 * 4) = ub;
    if (OutF) st4(OutF + (size_t)grow * 128 + c4 * 4, make_float4(o0, o1, o2, o3));
  }
}

// ---------- edge score: sc = K[src]*Q[dst]*0.25*pe (in place), w per head ----------
__global__ __launch_bounds__(256)
void edge_score_k(const ushort_t* __restrict__ Q, const ushort_t* __restrict__ K,
                  ushort_t* __restrict__ PE,
                  const int* __restrict__ src, const int* __restrict__ dst,
                  float* __restrict__ wbuf)
{
  int t = blockIdx.x * 256 + threadIdx.x;
  int e = t >> 4;
  if (e >= NE) return;
  int j = t & 15;
  int s = src[e], d = dst[e];
  u16x8 kv = *reinterpret_cast<const u16x8*>(K + (size_t)s * 128 + j * 8);
  u16x8 qv = *reinterpret_cast<const u16x8*>(Q + (size_t)d * 128 + j * 8);
  u16x8 pv = *reinterpret_cast<const u16x8*>(PE + (size_t)e * 128 + j * 8);
  float hsum = 0.f;
  u16x8 ob;
#pragma unroll
  for (int i = 0; i < 8; ++i) {
    float x = bf2f(kv[i]) * bf2f(qv[i]) * 0.25f * bf2f(pv[i]);
    hsum += x; ob[i] = f2bfu(x);
  }
  *reinterpret_cast<u16x8*>(PE + (size_t)e * 128 + j * 8) = ob;
  hsum += __shfl_xor(hsum, 1);               // pair shares the 16-ch head
  float w = expf(fminf(fmaxf(hsum, -5.f), 5.f));
  if ((j & 1) == 0) wbuf[(size_t)e * 8 + (j >> 1)] = w;
}

// ---------- CSR gather-reduce: h_att[n] = (sum w*V[src]) / (sum w + 1e-6) ----------
__global__ __launch_bounds__(256)
void reduce_k(const ushort_t* __restrict__ V, const float* __restrict__ wbuf,
              const int* __restrict__ start, const int2* __restrict__ csr_es,
              ushort_t* __restrict__ out)
{
  int t = blockIdx.x * 256 + threadIdx.x;
  int n = t >> 4;
  if (n >= NN) return;
  int j = t & 15;
  int p0 = start[n], p1 = start[n + 1];
  long long acc[8] = {};
  long long zacc = 0;
  for (int p = p0; p < p1; ++p) {
    int2 es = csr_es[p];
    float w = wbuf[(size_t)es.x * 8 + (j >> 1)];
    u16x8 vv = *reinterpret_cast<const u16x8*>(V + (size_t)es.y * 128 + j * 8);
    zacc += f2fx(w);
#pragma unroll
    for (int i = 0; i < 8; ++i) acc[i] += f2fx(bf2f(vv[i]) * w);
  }
  float zz = fx2f(zacc) + 1e-6f;
  u16x8 ob;
#pragma unroll
  for (int i = 0; i < 8; ++i) ob[i] = f2bfu(fx2f(acc[i]) / zz);
  *reinterpret_cast<u16x8*>(out + (size_t)n * 128 + j * 8) = ob;
}

// ---------- per-graph mean over 1000 nodes ----------
__global__ __launch_bounds__(256)
void graphmean_k(const float* __restrict__ h, float* __restrict__ hg)
{
  __shared__ float red[256];
  int g = blockIdx.x, tid = threadIdx.x;
  int c = tid & 127, half = tid >> 7;
  float s = 0.f;
  for (int r = half; r < 1000; r += 2) s += h[(size_t)(g * 1000 + r) * 128 + c];
  red[tid] = s;
  __syncthreads();
  if (half == 0) hg[g * 128 + c] = (red[c] + red[c + 128]) / 1000.0f;
}

// ---------- readout MLP: 128 -> 64 -> 32 -> 1 ----------
__global__ __launch_bounds__(256)
void readout_k(const float* __restrict__ hg,
               const float* __restrict__ w0, const float* __restrict__ b0,
               const float* __restrict__ w1, const float* __restrict__ b1,
               const float* __restrict__ w2, const float* __restrict__ b2,
               float* __restrict__ out)
{
  __shared__ float hs[25 * 128];
  __shared__ float t0[25 * 64];
  __shared__ float t1[25 * 32];
  int tid = threadIdx.x;
  for (int i = tid; i < 25 * 128; i += 256) hs[i] = hg[i];
  __syncthreads();
  for (int i = tid; i < 25 * 64; i += 256) {
    int r = i >> 6, c = i & 63;
    float a = b0[c];
    for (int k = 0; k < 128; k++) a += hs[r * 128 + k] * w0[k * 64 + c];
    t0[i] = fmaxf(a, 0.f);
  }
  __syncthreads();
  for (int i = tid; i < 25 * 32; i += 256) {
    int r = i >> 5, c = i & 31;
    float a = b1[c];
    for (int k = 0; k < 64; k++) a += t0[r * 64 + k] * w1[k * 32 + c];
    t1[i] = fmaxf(a, 0.f);
  }
  __syncthreads();
  if (tid < 25) {
    float a = b2[0];
    for (int k = 0; k < 32; k++) a += t1[tid * 32 + k] * w2[k];
    out[tid] = a;
  }
}

extern "C" void kernel_launch(void* const* d_in, const int* in_sizes, int n_in,
                              void* d_out, int out_size, void* d_ws, size_t ws_size,
                              hipStream_t stream)
{
  const float* emb_h  = (const float*)d_in[0];
  const float* emb_e  = (const float*)d_in[1];
  const float* w_qkve = (const float*)d_in[2];
  const float* o_w    = (const float*)d_in[3];
  const float* o_b    = (const float*)d_in[4];
  const float* ln_s   = (const float*)d_in[5];
  const float* ln_b   = (const float*)d_in[6];
  const float* ffn_w1 = (const float*)d_in[7];
  const float* ffn_b1 = (const float*)d_in[8];
  const float* ffn_w2 = (const float*)d_in[9];
  const float* ffn_b2 = (const float*)d_in[10];
  const float* mlp_w0 = (const float*)d_in[11];
  const float* mlp_b0 = (const float*)d_in[12];
  const float* mlp_w1 = (const float*)d_in[13];
  const float* mlp_b1 = (const float*)d_in[14];
  const float* mlp_w2 = (const float*)d_in[15];
  const float* mlp_b2 = (const float*)d_in[16];
  const int* tokens = (const int*)d_in[17];
  const int* etype  = (const int*)d_in[18];
  const int* src    = (const int*)d_in[19];
  const int* dst    = (const int*)d_in[20];

  // ---- workspace (~219 MB; <= 237 MB known-good) ----
  char* ws = (char*)d_ws;
  size_t off = 0;
  auto alloc = [&](size_t bytes) { char* p = ws + off; off += bytes; return p; };
  int2*      csr_es = (int2*)alloc((size_t)NE * 8);
  float*     h      = (float*)alloc((size_t)NN * 128 * 4);
  float*     hg     = (float*)alloc(25 * 128 * 4);
  float*     wbuf   = (float*)alloc((size_t)NE * 8 * 4);
  int*       counts = (int*)alloc((size_t)NN * 4);
  int*       cursor = (int*)alloc((size_t)NN * 4);
  int*       startp = (int*)alloc((size_t)(NN + 1) * 4);
  ushort_t*  h_bf   = (ushort_t*)alloc((size_t)NN * 128 * 2);
  ushort_t*  ha_bf  = (ushort_t*)alloc((size_t)NN * 128 * 2);
  ushort_t*  Qb     = (ushort_t*)alloc((size_t)NN * 128 * 2);   // Q,K,V contiguous (osep)
  ushort_t*  Kb     = (ushort_t*)alloc((size_t)NN * 128 * 2);
  ushort_t*  Vb     = (ushort_t*)alloc((size_t)NN * 128 * 2);
  ushort_t*  e_bf   = (ushort_t*)alloc((size_t)NE * 128 * 2);
  ushort_t*  sc_bf  = (ushort_t*)alloc((size_t)NE * 128 * 2);
  ushort_t*  wt     = (ushort_t*)alloc(917504 * 2);
  (void)Kb; (void)Vb;

  // packed transposed bf16 weights
  ushort_t* qkveT = wt;            // 16 mats [128][128]
  ushort_t* owT   = wt + 262144;   // 8 mats  [128][128]
  ushort_t* w1T   = wt + 393216;   // 8 mats  [256][128]
  ushort_t* w2T   = wt + 655360;   // 8 mats  [128][256]
  wconv_k<<<1024, 256, 0, stream>>>(w_qkve, qkveT, 128, 128, 262144);
  wconv_k<<<512,  256, 0, stream>>>(o_w,    owT,   128, 128, 131072);
  wconv_k<<<1024, 256, 0, stream>>>(ffn_w1, w1T,   128, 256, 262144);
  wconv_k<<<1024, 256, 0, stream>>>(ffn_w2, w2T,   256, 128, 262144);

  gather_h_k<<<3125, 256, 0, stream>>>(emb_h, tokens, h, h_bf);
  gather_e_k<<<37500, 256, 0, stream>>>(emb_e, etype, e_bf);

  // CSR by dst (shared across layers)
  hipMemsetAsync(counts, 0, (size_t)NN * 4, stream);
  count_k<<<(NE + 255) / 256, 256, 0, stream>>>(dst, counts);
  scan_k<<<1, 1024, 0, stream>>>(counts, startp, cursor);
  scatter_k<<<(NE + 255) / 256, 256, 0, stream>>>(src, dst, cursor, csr_es);

  const int GN = (NN + 127) / 128;    // 196
  const int GE = (NE + 127) / 128;    // 2344
  const int FN = (NN + 63) / 64;      // 391
  const int FE = (NE + 63) / 64;      // 4688

  for (int l = 0; l < 4; ++l) {
    const ushort_t* qkvT = qkveT + (size_t)l * 4 * 16384;          // wq|wk|wv rows 0..383
    const ushort_t* weT  = qkveT + ((size_t)l * 4 + 3) * 16384;
    const ushort_t* ow0T = owT + ((size_t)l * 2 + 0) * 16384;
    const ushort_t* ow1T = owT + ((size_t)l * 2 + 1) * 16384;
    const ushort_t* w1hT = w1T + ((size_t)l * 2 + 0) * 32768;
    const ushort_t* w1eT = w1T + ((size_t)l * 2 + 1) * 32768;
    const ushort_t* w2hT = w2T + ((size_t)l * 2 + 0) * 32768;
    const ushort_t* w2eT = w2T + ((size_t)l * 2 + 1) * 32768;
    const float* ob0 = o_b + ((size_t)l * 2 + 0) * 128;
    const float* ob1 = o_b + ((size_t)l * 2 + 1) * 128;
    const float* ls0 = ln_s + ((size_t)l * 4 + 0) * 128;
    const float* ls1 = ln_s + ((size_t)l * 4 + 1) * 128;
    const float* ls2 = ln_s + ((size_t)l * 4 + 2) * 128;
    const float* ls3 = ln_s + ((size_t)l * 4 + 3) * 128;
    const float* lb0 = ln_b + ((size_t)l * 4 + 0) * 128;
    const float* lb1 = ln_b + ((size_t)l * 4 + 1) * 128;
    const float* lb2 = ln_b + ((size_t)l * 4 + 2) * 128;
    const float* lb3 = ln_b + ((size_t)l * 4 + 3) * 128;
    const float* fb1h = ffn_b1 + ((size_t)l * 2 + 0) * 256;
    const float* fb1e = ffn_b1 + ((size_t)l * 2 + 1) * 256;
    const float* fb2h = ffn_b2 + ((size_t)l * 2 + 0) * 128;
    const float* fb2e = ffn_b2 + ((size_t)l * 2 + 1) * 128;

    // fused QKV (osep): y selects weight mat + output buffer
    gemmN_bf_k<<<dim3(GN, 3), 256, 0, stream>>>(h_bf, qkvT, 128, NN, 128,
        nullptr, 1, nullptr, nullptr, nullptr, nullptr, Qb, nullptr);
    // pe projection
    gemmN_bf_k<<<dim3(GE, 1), 256, 0, stream>>>(e_bf, weT, 128, NE, 128,
        nullptr, 0, nullptr, nullptr, nullptr, nullptr, sc_bf, nullptr);

    edge_score_k<<<18750, 256, 0, stream>>>(Qb, Kb, sc_bf, src, dst, wbuf);
    reduce_k<<<1563, 256, 0, stream>>>(Vb, wbuf, startp, csr_es, ha_bf);

    // h = LN(h + h_att@O_h + b); dual write fp32+bf16
    gemmN_bf_k<<<dim3(GN, 1), 256, 0, stream>>>(ha_bf, ow0T, 128, NN, 128,
        ob0, 0, h, nullptr, ls0, lb0, h_bf, h);
    // e = LN(e + e_att@O_e + b)
    gemmN_bf_k<<<dim3(GE, 1), 256, 0, stream>>>(sc_bf, ow1T, 128, NE, 128,
        ob1, 0, nullptr, e_bf, ls1, lb1, e_bf, nullptr);

    // fused FFNs (Mid in LDS only)
    ffn_f_k<<<FN, 256, 0, stream>>>(h_bf, h, w1hT, fb1h, w2hT, fb2h,
                                    ls2, lb2, h_bf, h, NN);
    ffn_f_k<<<FE, 256, 0, stream>>>(e_bf, nullptr, w1eT, fb1e, w2eT, fb2e,
                                    ls3, lb3, e_bf, nullptr, NE);
  }

  graphmean_k<<<25, 256, 0, stream>>>(h, hg);
  readout_k<<<1, 256, 0, stream>>>(hg, mlp_w0, mlp_b0, mlp_w1, mlp_b1, mlp_w2, mlp_b2,
                                   (float*)d_out);
}

// Round 8
// 1821.554 us; speedup vs baseline: 1.6719x; 1.2375x over previous
//
#include <hip/hip_runtime.h>
#include <cstdint>

#define NN 25000
#define NE 300000

typedef unsigned short ushort_t;
typedef __attribute__((ext_vector_type(8))) short bf16x8;
typedef __attribute__((ext_vector_type(4))) float f32x4;
typedef __attribute__((ext_vector_type(4))) unsigned short u16x4;
typedef __attribute__((ext_vector_type(8))) unsigned short u16x8;

__device__ __forceinline__ float4 ld4(const float* p){ return *reinterpret_cast<const float4*>(p); }
__device__ __forceinline__ void st4(float* p, const float4& v){ *reinterpret_cast<float4*>(p) = v; }
__device__ __forceinline__ float bf2f(ushort_t u){ return __uint_as_float((unsigned)u << 16); }
__device__ __forceinline__ ushort_t f2bfu(float f){
  unsigned x = __float_as_uint(f);
  return (ushort_t)((x + 0x7fffu + ((x >> 16) & 1u)) >> 16);   // RNE
}

// fixed-point (2^32): order-independent integer accumulation -> deterministic
#define FXS 4294967296.0
#define FXI 2.3283064365386963e-10
__device__ __forceinline__ long long f2fx(float v) {
  return (long long)llrint((double)v * FXS);
}
__device__ __forceinline__ float fx2f(long long q) { return (float)((double)q * FXI); }

#define MFMA(a, b, c) __builtin_amdgcn_mfma_f32_16x16x32_bf16((a), (b), (c), 0, 0, 0)

// ---------- weight convert+transpose: dst[mat][n][k] = bf16(src[mat][k][n]) ----------
__global__ __launch_bounds__(256)
void wconv_k(const float* __restrict__ src, ushort_t* __restrict__ dst,
             int K, int N, int total)
{
  int i = blockIdx.x * 256 + threadIdx.x;
  if (i >= total) return;
  int kn = K * N;
  int mat = i / kn, r = i - mat * kn;
  int n = r / K, k = r - n * K;
  dst[i] = f2bfu(src[(size_t)mat * kn + (size_t)k * N + n]);
}

// ---------- gathers ----------
__global__ __launch_bounds__(256)
void gather_h_k(const float* __restrict__ tab, const int* __restrict__ idx,
                float* __restrict__ hf, ushort_t* __restrict__ hb)
{
  int t = blockIdx.x * 256 + threadIdx.x;
  if (t >= NN * 32) return;
  int i = t >> 5, c4 = t & 31;
  float4 v = ld4(tab + (size_t)idx[i] * 128 + c4 * 4);
  st4(hf + (size_t)i * 128 + c4 * 4, v);
  u16x4 b = { f2bfu(v.x), f2bfu(v.y), f2bfu(v.z), f2bfu(v.w) };
  *reinterpret_cast<u16x4*>(hb + (size_t)i * 128 + c4 * 4) = b;
}

__global__ __launch_bounds__(256)
void gather_e_k(const float* __restrict__ tab, const int* __restrict__ idx,
                ushort_t* __restrict__ eb)
{
  int t = blockIdx.x * 256 + threadIdx.x;
  if (t >= NE * 32) return;
  int i = t >> 5, c4 = t & 31;
  float4 v = ld4(tab + (size_t)idx[i] * 128 + c4 * 4);
  u16x4 b = { f2bfu(v.x), f2bfu(v.y), f2bfu(v.z), f2bfu(v.w) };
  *reinterpret_cast<u16x4*>(eb + (size_t)i * 128 + c4 * 4) = b;
}

// ---------- CSR build (per call; graph shared by all 4 layers) ----------
__global__ __launch_bounds__(256)
void count_k(const int* __restrict__ dst, int* __restrict__ counts)
{
  int e = blockIdx.x * 256 + threadIdx.x;
  if (e < NE) atomicAdd(&counts[dst[e]], 1);
}

__global__ __launch_bounds__(1024)
void scan_k(const int* __restrict__ counts, int* __restrict__ start,
            int* __restrict__ cursor)
{
  __shared__ int part[1024];
  const int t = threadIdx.x;
  const int base = t * 25;
  int loc[25];
  int s = 0;
#pragma unroll
  for (int i = 0; i < 25; ++i) {
    int n = base + i;
    int c = (n < NN) ? counts[n] : 0;
    loc[i] = s; s += c;
  }
  part[t] = s;
  __syncthreads();
  for (int off = 1; off < 1024; off <<= 1) {
    int v = (t >= off) ? part[t - off] : 0;
    __syncthreads();
    part[t] += v;
    __syncthreads();
  }
  int excl = (t == 0) ? 0 : part[t - 1];
#pragma unroll
  for (int i = 0; i < 25; ++i) {
    int n = base + i;
    if (n < NN) { int v = excl + loc[i]; start[n] = v; cursor[n] = v; }
  }
  if (t == 0) start[NN] = NE;
}

__global__ __launch_bounds__(256)
void scatter_k(const int* __restrict__ src, const int* __restrict__ dst,
               int* __restrict__ cursor, int2* __restrict__ csr_es)
{
  int e = blockIdx.x * 256 + threadIdx.x;
  if (e >= NE) return;
  int pos = atomicAdd(&cursor[dst[e]], 1);    // order nondet; reduce is order-indep
  csr_es[pos] = make_int2(e, src[e]);
}

// ---------- MFMA GEMM: [M,K]@[K,N]; coalesced repack stores; opt bias+resid+LN ----
// used for QKV (osep) and O_h (LN epilogue). 70KB LDS -> 2 blocks/CU.
__global__ __launch_bounds__(256)
void gemmN_bf_k(const ushort_t* __restrict__ A, const ushort_t* __restrict__ WT,
                const int K, const int M, const int ldo,
                const float* __restrict__ Bias, const int osep,
                const float* __restrict__ ResF, const ushort_t* __restrict__ ResB,
                const float* __restrict__ G, const float* __restrict__ Bb,
                ushort_t* __restrict__ OutB, float* __restrict__ OutF)
{
  __shared__ __align__(16) ushort_t SM[2 * 128 * 136];
  __shared__ float mu[128], rs[128];
  ushort_t* Xs = SM;
  ushort_t* Ws = SM + 128 * 136;
  const int tid = threadIdx.x;
  const int m0 = blockIdx.x * 128;
  const int col0 = blockIdx.y * 128;

  const int l = tid & 63, wv = tid >> 6;
  const int lr = l & 15, lk = l >> 4;
  const int mb = (wv & 1) * 64, nb = (wv >> 1) * 64;
  f32x4 acc[4][4];
  const f32x4 zf = {0.f, 0.f, 0.f, 0.f};
#pragma unroll
  for (int mi = 0; mi < 4; ++mi)
#pragma unroll
    for (int ni = 0; ni < 4; ++ni) acc[mi][ni] = zf;

  for (int kc = 0; kc < K; kc += 128) {
    if (kc) __syncthreads();
    for (int c = tid; c < 2048; c += 256) {
      int r = c >> 4, k8 = c & 15;
      bf16x8 v = {};
      if (m0 + r < M)
        v = *reinterpret_cast<const bf16x8*>(A + (size_t)(m0 + r) * K + kc + k8 * 8);
      *reinterpret_cast<bf16x8*>(Xs + r * 136 + k8 * 8) = v;
    }
    for (int c = tid; c < 2048; c += 256) {
      int r = c >> 4, k8 = c & 15;
      *reinterpret_cast<bf16x8*>(Ws + r * 136 + k8 * 8) =
          *reinterpret_cast<const bf16x8*>(WT + (size_t)(col0 + r) * K + kc + k8 * 8);
    }
    __syncthreads();
#pragma unroll
    for (int kt = 0; kt < 4; ++kt) {
      bf16x8 af[4], bw[4];
#pragma unroll
      for (int i = 0; i < 4; ++i)
        af[i] = *reinterpret_cast<const bf16x8*>(Xs + (mb + i * 16 + lr) * 136 + kt * 32 + lk * 8);
#pragma unroll
      for (int i = 0; i < 4; ++i)
        bw[i] = *reinterpret_cast<const bf16x8*>(Ws + (nb + i * 16 + lr) * 136 + kt * 32 + lk * 8);
#pragma unroll
      for (int mi = 0; mi < 4; ++mi)
#pragma unroll
        for (int ni = 0; ni < 4; ++ni)
          acc[mi][ni] = MFMA(af[mi], bw[ni], acc[mi][ni]);
    }
  }

  if (G == nullptr) {
    __syncthreads();
    ushort_t* Rb = SM;
#pragma unroll
    for (int mi = 0; mi < 4; ++mi)
#pragma unroll
      for (int rr = 0; rr < 4; ++rr) {
        int row = mb + mi * 16 + lk * 4 + rr;
#pragma unroll
        for (int ni = 0; ni < 4; ++ni) {
          int col = nb + ni * 16 + lr;
          float v = acc[mi][ni][rr];
          if (Bias) v = fmaxf(v + Bias[col0 + col], 0.f);
          Rb[row * 136 + col] = f2bfu(v);
        }
      }
    __syncthreads();
    ushort_t* ob = OutB + (osep ? (size_t)blockIdx.y * M * 128 : (size_t)col0);
    for (int c = tid; c < 2048; c += 256) {
      int r = c >> 4, k8 = c & 15;
      if (m0 + r < M)
        *reinterpret_cast<u16x8*>(ob + (size_t)(m0 + r) * ldo + k8 * 8) =
            *reinterpret_cast<u16x8*>(Rb + r * 136 + k8 * 8);
    }
    return;
  }

  // LN epilogue
  __syncthreads();
  float* Tf = reinterpret_cast<float*>(SM);
#pragma unroll
  for (int mi = 0; mi < 4; ++mi)
#pragma unroll
    for (int rr = 0; rr < 4; ++rr) {
      int row = mb + mi * 16 + lk * 4 + rr;
      int grow = m0 + row;
#pragma unroll
      for (int ni = 0; ni < 4; ++ni) {
        int col = nb + ni * 16 + lr;
        float t = acc[mi][ni][rr] + Bias[col];
        if (grow < M)
          t += ResF ? ResF[(size_t)grow * 128 + col] : bf2f(ResB[(size_t)grow * 128 + col]);
        Tf[row * 132 + col] = t;
      }
    }
  __syncthreads();
  {
    int r = tid >> 1, jj = tid & 1;
    const float* tp = Tf + r * 132 + jj * 64;
    float s = 0.f;
    for (int c2 = 0; c2 < 64; ++c2) s += tp[c2];
    s += __shfl_xor(s, 1);
    float mean = s * (1.f / 128.f);
    float v = 0.f;
    for (int c2 = 0; c2 < 64; ++c2) { float d = tp[c2] - mean; v += d * d; }
    v += __shfl_xor(v, 1);
    if (jj == 0) { mu[r] = mean; rs[r] = 1.f / sqrtf(v * (1.f / 128.f) + 1e-5f); }
  }
  __syncthreads();
  for (int c = tid; c < 4096; c += 256) {
    int r = c >> 5, c4 = c & 31;
    int grow = m0 + r;
    if (grow >= M) continue;
    float4 t = ld4(Tf + r * 132 + c4 * 4);
    float4 gv = ld4(G + c4 * 4), bv = ld4(Bb + c4 * 4);
    float m = mu[r], ir = rs[r];
    float o0 = gv.x * (t.x - m) * ir + bv.x;
    float o1 = gv.y * (t.y - m) * ir + bv.y;
    float o2 = gv.z * (t.z - m) * ir + bv.z;
    float o3 = gv.w * (t.w - m) * ir + bv.w;
    u16x4 ub = { f2bfu(o0), f2bfu(o1), f2bfu(o2), f2bfu(o3) };
    *reinterpret_cast<u16x4*>(OutB + (size_t)grow * 128 + c4 * 4) = ub;
    if (OutF) st4(OutF + (size_t)grow * 128 + c4 * 4, make_float4(o0, o1, o2, o3));
  }
}

// ---------- fused h-FFN (unchanged from round 7) ----------
__global__ __launch_bounds__(256)
void ffn_f_k(const ushort_t* __restrict__ Xbf, const float* __restrict__ ResF,
             const ushort_t* __restrict__ W1T, const float* __restrict__ B1,
             const ushort_t* __restrict__ W2T, const float* __restrict__ B2,
             const float* __restrict__ G, const float* __restrict__ Bb,
             ushort_t* __restrict__ OutB, float* __restrict__ OutF, int M)
{
  __shared__ __align__(16) ushort_t SM[8704 + 8704 + 17408];
  __shared__ float mu[64], rs[64];
  ushort_t* Xs   = SM;
  ushort_t* Mid0 = SM + 8704;
  ushort_t* Wst  = SM + 17408;
  const int tid = threadIdx.x;
  const int m0 = blockIdx.x * 64;
  const int l = tid & 63, wv = tid >> 6, lr = l & 15, lk = l >> 4;
  const f32x4 zf = {0.f, 0.f, 0.f, 0.f};

  for (int c = tid; c < 1024; c += 256) {
    int r = c >> 4, k8 = c & 15;
    bf16x8 v = {};
    if (m0 + r < M) v = *reinterpret_cast<const bf16x8*>(Xbf + (size_t)(m0 + r) * 128 + k8 * 8);
    *reinterpret_cast<bf16x8*>(Xs + r * 136 + k8 * 8) = v;
  }
  for (int c = tid; c < 2048; c += 256) {
    int r = c >> 4, k8 = c & 15;
    *reinterpret_cast<bf16x8*>(Wst + r * 136 + k8 * 8) =
        *reinterpret_cast<const bf16x8*>(W1T + (size_t)r * 128 + k8 * 8);
  }
  __syncthreads();

  f32x4 acc2[8];
#pragma unroll
  for (int i = 0; i < 8; ++i) acc2[i] = zf;
  ushort_t rsv[8][4];

  {
    f32x4 a1[8];
#pragma unroll
    for (int i = 0; i < 8; ++i) a1[i] = zf;
#pragma unroll
    for (int kt = 0; kt < 4; ++kt) {
      bf16x8 af = *reinterpret_cast<const bf16x8*>(Xs + (wv * 16 + lr) * 136 + kt * 32 + lk * 8);
#pragma unroll
      for (int ni = 0; ni < 8; ++ni) {
        bf16x8 bw = *reinterpret_cast<const bf16x8*>(Wst + (ni * 16 + lr) * 136 + kt * 32 + lk * 8);
        a1[ni] = MFMA(af, bw, a1[ni]);
      }
    }
#pragma unroll
    for (int ni = 0; ni < 8; ++ni)
#pragma unroll
      for (int rr = 0; rr < 4; ++rr)
        Mid0[(wv * 16 + lk * 4 + rr) * 136 + ni * 16 + lr] =
            f2bfu(fmaxf(a1[ni][rr] + B1[ni * 16 + lr], 0.f));
  }
  __syncthreads();
  for (int c = tid; c < 2048; c += 256) {
    int r = c >> 4, k8 = c & 15;
    *reinterpret_cast<bf16x8*>(Wst + r * 136 + k8 * 8) =
        *reinterpret_cast<const bf16x8*>(W1T + (size_t)(128 + r) * 128 + k8 * 8);
  }
  __syncthreads();
  {
    f32x4 a1[8];
#pragma unroll
    for (int i = 0; i < 8; ++i) a1[i] = zf;
#pragma unroll
    for (int kt = 0; kt < 4; ++kt) {
      bf16x8 af = *reinterpret_cast<const bf16x8*>(Xs + (wv * 16 + lr) * 136 + kt * 32 + lk * 8);
#pragma unroll
      for (int ni = 0; ni < 8; ++ni) {
        bf16x8 bw = *reinterpret_cast<const bf16x8*>(Wst + (ni * 16 + lr) * 136 + kt * 32 + lk * 8);
        a1[ni] = MFMA(af, bw, a1[ni]);
      }
    }
    __syncthreads();
    if (!ResF) {
#pragma unroll
      for (int ni = 0; ni < 8; ++ni)
#pragma unroll
        for (int rr = 0; rr < 4; ++rr)
          rsv[ni][rr] = Xs[(wv * 16 + lk * 4 + rr) * 136 + ni * 16 + lr];
    }
#pragma unroll
    for (int ni = 0; ni < 8; ++ni)
#pragma unroll
      for (int rr = 0; rr < 4; ++rr)
        Xs[(wv * 16 + lk * 4 + rr) * 136 + ni * 16 + lr] =
            f2bfu(fmaxf(a1[ni][rr] + B1[128 + ni * 16 + lr], 0.f));
  }
  __syncthreads();
  for (int c = tid; c < 2048; c += 256) {
    int r = c >> 4, k8 = c & 15;
    *reinterpret_cast<bf16x8*>(Wst + r * 136 + k8 * 8) =
        *reinterpret_cast<const bf16x8*>(W2T + (size_t)r * 256 + k8 * 8);
  }
  __syncthreads();
#pragma unroll
  for (int kt = 0; kt < 4; ++kt) {
    bf16x8 af = *reinterpret_cast<const bf16x8*>(Mid0 + (wv * 16 + lr) * 136 + kt * 32 + lk * 8);
#pragma unroll
    for (int ni = 0; ni < 8; ++ni) {
      bf16x8 bw = *reinterpret_cast<const bf16x8*>(Wst + (ni * 16 + lr) * 136 + kt * 32 + lk * 8);
      acc2[ni] = MFMA(af, bw, acc2[ni]);
    }
  }
  __syncthreads();
  for (int c = tid; c < 2048; c += 256) {
    int r = c >> 4, k8 = c & 15;
    *reinterpret_cast<bf16x8*>(Wst + r * 136 + k8 * 8) =
        *reinterpret_cast<const bf16x8*>(W2T + (size_t)r * 256 + 128 + k8 * 8);
  }
  __syncthreads();
#pragma unroll
  for (int kt = 0; kt < 4; ++kt) {
    bf16x8 af = *reinterpret_cast<const bf16x8*>(Xs + (wv * 16 + lr) * 136 + kt * 32 + lk * 8);
#pragma unroll
    for (int ni = 0; ni < 8; ++ni) {
      bf16x8 bw = *reinterpret_cast<const bf16x8*>(Wst + (ni * 16 + lr) * 136 + kt * 32 + lk * 8);
      acc2[ni] = MFMA(af, bw, acc2[ni]);
    }
  }
  __syncthreads();
  float* Tf = reinterpret_cast<float*>(Wst);
#pragma unroll
  for (int ni = 0; ni < 8; ++ni)
#pragma unroll
    for (int rr = 0; rr < 4; ++rr) {
      int row = wv * 16 + lk * 4 + rr;
      int grow = m0 + row;
      int col = ni * 16 + lr;
      float t = acc2[ni][rr] + B2[col];
      if (ResF) { if (grow < M) t += ResF[(size_t)grow * 128 + col]; }
      else      t += bf2f(rsv[ni][rr]);
      Tf[row * 132 + col] = t;
    }
  __syncthreads();
  {
    int r = tid >> 2, jj = tid & 3;
    const float* tp = Tf + r * 132 + jj * 32;
    float s = 0.f;
    for (int c2 = 0; c2 < 32; ++c2) s += tp[c2];
    s += __shfl_xor(s, 1); s += __shfl_xor(s, 2);
    float mean = s * (1.f / 128.f);
    float v = 0.f;
    for (int c2 = 0; c2 < 32; ++c2) { float d = tp[c2] - mean; v += d * d; }
    v += __shfl_xor(v, 1); v += __shfl_xor(v, 2);
    if (jj == 0) { mu[r] = mean; rs[r] = 1.f / sqrtf(v * (1.f / 128.f) + 1e-5f); }
  }
  __syncthreads();
  for (int c = tid; c < 2048; c += 256) {
    int r = c >> 5, c4 = c & 31;
    int grow = m0 + r;
    if (grow >= M) continue;
    float4 t = ld4(Tf + r * 132 + c4 * 4);
    float4 gv = ld4(G + c4 * 4), bv = ld4(Bb + c4 * 4);
    float m = mu[r], ir = rs[r];
    float o0 = gv.x * (t.x - m) * ir + bv.x;
    float o1 = gv.y * (t.y - m) * ir + bv.y;
    float o2 = gv.z * (t.z - m) * ir + bv.z;
    float o3 = gv.w * (t.w - m) * ir + bv.w;
    u16x4 ub = { f2bfu(o0), f2bfu(o1), f2bfu(o2), f2bfu(o3) };
    *reinterpret_cast<u16x4*>(OutB + (size_t)grow * 128 + c4 * 4) = ub;
    if (OutF) st4(OutF + (size_t)grow * 128 + c4 * 4, make_float4(o0, o1, o2, o3));
  }
}

// ---------- e-side mega-fusion: pe -> score -> O_e+LN -> FFN+LN, 64 e-rows/block ----
// Es [64][136] | Mid0 [64][136] | Wst [128][136] (reused as Tf f32 [64][132]). ~70KB.
// pe, sc, e1 never touch HBM. In-place on Ebuf (block-local rows). Emits wbuf.
__global__ __launch_bounds__(256)
void efused_k(ushort_t* __restrict__ Ebuf,
              const ushort_t* __restrict__ Qb, const ushort_t* __restrict__ Kb,
              const int* __restrict__ src, const int* __restrict__ dst,
              float* __restrict__ wbuf,
              const ushort_t* __restrict__ weT,
              const ushort_t* __restrict__ owT, const float* __restrict__ oBias,
              const float* __restrict__ G1, const float* __restrict__ B1n,
              const ushort_t* __restrict__ W1T, const float* __restrict__ fB1,
              const ushort_t* __restrict__ W2T, const float* __restrict__ fB2,
              const float* __restrict__ G2, const float* __restrict__ B2n,
              int M)
{
  __shared__ __align__(16) ushort_t SM[34816];
  __shared__ float mu[64], rs[64];
  ushort_t* Es   = SM;            // e tile -> e1 tile -> Mid1
  ushort_t* Mid0 = SM + 8704;     // pe -> sc -> FFN Mid lo
  ushort_t* Wst  = SM + 17408;    // weight stage / Tf f32 [64][132]
  const int tid = threadIdx.x;
  const int m0 = blockIdx.x * 64;
  const int l = tid & 63, wv = tid >> 6, lr = l & 15, lk = l >> 4;
  const f32x4 zf = {0.f, 0.f, 0.f, 0.f};

  // P1: stage e tile + weT
  for (int c = tid; c < 1024; c += 256) {
    int r = c >> 4, k8 = c & 15;
    bf16x8 v = {};
    if (m0 + r < M) v = *reinterpret_cast<const bf16x8*>(Ebuf + (size_t)(m0 + r) * 128 + k8 * 8);
    *reinterpret_cast<bf16x8*>(Es + r * 136 + k8 * 8) = v;
  }
  for (int c = tid; c < 2048; c += 256) {
    int r = c >> 4, k8 = c & 15;
    *reinterpret_cast<bf16x8*>(Wst + r * 136 + k8 * 8) =
        *reinterpret_cast<const bf16x8*>(weT + (size_t)r * 128 + k8 * 8);
  }
  __syncthreads();

  // P2: pe = Es @ weT -> Mid0 (bf16, no bias)
  {
    f32x4 a1[8];
#pragma unroll
    for (int i = 0; i < 8; ++i) a1[i] = zf;
#pragma unroll
    for (int kt = 0; kt < 4; ++kt) {
      bf16x8 af = *reinterpret_cast<const bf16x8*>(Es + (wv * 16 + lr) * 136 + kt * 32 + lk * 8);
#pragma unroll
      for (int ni = 0; ni < 8; ++ni) {
        bf16x8 bw = *reinterpret_cast<const bf16x8*>(Wst + (ni * 16 + lr) * 136 + kt * 32 + lk * 8);
        a1[ni] = MFMA(af, bw, a1[ni]);
      }
    }
#pragma unroll
    for (int ni = 0; ni < 8; ++ni)
#pragma unroll
      for (int rr = 0; rr < 4; ++rr)
        Mid0[(wv * 16 + lk * 4 + rr) * 136 + ni * 16 + lr] = f2bfu(a1[ni][rr]);
  }
  __syncthreads();

  // P3: score in place on Mid0: sc = K[src]*Q[dst]*0.25*pe; w = exp(clip(head sums))
  for (int c = tid; c < 1024; c += 256) {
    int r = c >> 4, j = c & 15;
    int e = m0 + r;
    if (e < M) {
      int s = src[e], d = dst[e];
      u16x8 kv = *reinterpret_cast<const u16x8*>(Kb + (size_t)s * 128 + j * 8);
      u16x8 qv = *reinterpret_cast<const u16x8*>(Qb + (size_t)d * 128 + j * 8);
      u16x8 pv = *reinterpret_cast<const u16x8*>(Mid0 + r * 136 + j * 8);
      float hsum = 0.f;
      u16x8 ob;
#pragma unroll
      for (int i = 0; i < 8; ++i) {
        float x = bf2f(kv[i]) * bf2f(qv[i]) * 0.25f * bf2f(pv[i]);
        hsum += x; ob[i] = f2bfu(x);
      }
      *reinterpret_cast<u16x8*>(Mid0 + r * 136 + j * 8) = ob;
      hsum += __shfl_xor(hsum, 1);   // pair tid^1 has same r, j^1
      float w = expf(fminf(fmaxf(hsum, -5.f), 5.f));
      if ((j & 1) == 0) wbuf[(size_t)e * 8 + (j >> 1)] = w;
    }
  }
  __syncthreads();

  // P4: stage owT
  for (int c = tid; c < 2048; c += 256) {
    int r = c >> 4, k8 = c & 15;
    *reinterpret_cast<bf16x8*>(Wst + r * 136 + k8 * 8) =
        *reinterpret_cast<const bf16x8*>(owT + (size_t)r * 128 + k8 * 8);
  }
  __syncthreads();

  // P5: O_e = sc @ owT -> a1; P6: Tf = a1 + oBias + resid(Es); LN1 -> e1 -> Es
  {
    f32x4 a1[8];
#pragma unroll
    for (int i = 0; i < 8; ++i) a1[i] = zf;
#pragma unroll
    for (int kt = 0; kt < 4; ++kt) {
      bf16x8 af = *reinterpret_cast<const bf16x8*>(Mid0 + (wv * 16 + lr) * 136 + kt * 32 + lk * 8);
#pragma unroll
      for (int ni = 0; ni < 8; ++ni) {
        bf16x8 bw = *reinterpret_cast<const bf16x8*>(Wst + (ni * 16 + lr) * 136 + kt * 32 + lk * 8);
        a1[ni] = MFMA(af, bw, a1[ni]);
      }
    }
    __syncthreads();   // Wst reads done -> reuse as Tf
    float* Tf = reinterpret_cast<float*>(Wst);
#pragma unroll
    for (int ni = 0; ni < 8; ++ni)
#pragma unroll
      for (int rr = 0; rr < 4; ++rr) {
        int row = wv * 16 + lk * 4 + rr;
        int col = ni * 16 + lr;
        Tf[row * 132 + col] = a1[ni][rr] + oBias[col] + bf2f(Es[row * 136 + col]);
      }
  }
  __syncthreads();
  {
    float* Tf = reinterpret_cast<float*>(Wst);
    int r = tid >> 2, jj = tid & 3;
    const float* tp = Tf + r * 132 + jj * 32;
    float s = 0.f;
    for (int c2 = 0; c2 < 32; ++c2) s += tp[c2];
    s += __shfl_xor(s, 1); s += __shfl_xor(s, 2);
    float mean = s * (1.f / 128.f);
    float v = 0.f;
    for (int c2 = 0; c2 < 32; ++c2) { float d = tp[c2] - mean; v += d * d; }
    v += __shfl_xor(v, 1); v += __shfl_xor(v, 2);
    if (jj == 0) { mu[r] = mean; rs[r] = 1.f / sqrtf(v * (1.f / 128.f) + 1e-5f); }
  }
  __syncthreads();
  {
    float* Tf = reinterpret_cast<float*>(Wst);
    for (int c = tid; c < 2048; c += 256) {
      int r = c >> 5, c4 = c & 31;
      float4 t = ld4(Tf + r * 132 + c4 * 4);
      float4 gv = ld4(G1 + c4 * 4), bv = ld4(B1n + c4 * 4);
      float m = mu[r], ir = rs[r];
      u16x4 ub = { f2bfu(gv.x * (t.x - m) * ir + bv.x), f2bfu(gv.y * (t.y - m) * ir + bv.y),
                   f2bfu(gv.z * (t.z - m) * ir + bv.z), f2bfu(gv.w * (t.w - m) * ir + bv.w) };
      *reinterpret_cast<u16x4*>(Es + r * 136 + c4 * 4) = ub;   // e1 (also FFN resid)
    }
  }
  __syncthreads();

  // ---- FFN on Es (= e1), identical to ffn_f_k e-path ----
  f32x4 acc2[8];
#pragma unroll
  for (int i = 0; i < 8; ++i) acc2[i] = zf;
  ushort_t rsv[8][4];

  for (int c = tid; c < 2048; c += 256) {   // stage W1a
    int r = c >> 4, k8 = c & 15;
    *reinterpret_cast<bf16x8*>(Wst + r * 136 + k8 * 8) =
        *reinterpret_cast<const bf16x8*>(W1T + (size_t)r * 128 + k8 * 8);
  }
  __syncthreads();
  {
    f32x4 a1[8];
#pragma unroll
    for (int i = 0; i < 8; ++i) a1[i] = zf;
#pragma unroll
    for (int kt = 0; kt < 4; ++kt) {
      bf16x8 af = *reinterpret_cast<const bf16x8*>(Es + (wv * 16 + lr) * 136 + kt * 32 + lk * 8);
#pragma unroll
      for (int ni = 0; ni < 8; ++ni) {
        bf16x8 bw = *reinterpret_cast<const bf16x8*>(Wst + (ni * 16 + lr) * 136 + kt * 32 + lk * 8);
        a1[ni] = MFMA(af, bw, a1[ni]);
      }
    }
    __syncthreads();   // Mid0 sc reads done (P5) -> overwrite
#pragma unroll
    for (int ni = 0; ni < 8; ++ni)
#pragma unroll
      for (int rr = 0; rr < 4; ++rr)
        Mid0[(wv * 16 + lk * 4 + rr) * 136 + ni * 16 + lr] =
            f2bfu(fmaxf(a1[ni][rr] + fB1[ni * 16 + lr], 0.f));
  }
  __syncthreads();
  for (int c = tid; c < 2048; c += 256) {   // stage W1b
    int r = c >> 4, k8 = c & 15;
    *reinterpret_cast<bf16x8*>(Wst + r * 136 + k8 * 8) =
        *reinterpret_cast<const bf16x8*>(W1T + (size_t)(128 + r) * 128 + k8 * 8);
  }
  __syncthreads();
  {
    f32x4 a1[8];
#pragma unroll
    for (int i = 0; i < 8; ++i) a1[i] = zf;
#pragma unroll
    for (int kt = 0; kt < 4; ++kt) {
      bf16x8 af = *reinterpret_cast<const bf16x8*>(Es + (wv * 16 + lr) * 136 + kt * 32 + lk * 8);
#pragma unroll
      for (int ni = 0; ni < 8; ++ni) {
        bf16x8 bw = *reinterpret_cast<const bf16x8*>(Wst + (ni * 16 + lr) * 136 + kt * 32 + lk * 8);
        a1[ni] = MFMA(af, bw, a1[ni]);
      }
    }
    __syncthreads();   // all Es reads done
#pragma unroll
    for (int ni = 0; ni < 8; ++ni)
#pragma unroll
      for (int rr = 0; rr < 4; ++rr)
        rsv[ni][rr] = Es[(wv * 16 + lk * 4 + rr) * 136 + ni * 16 + lr];   // save e1
#pragma unroll
    for (int ni = 0; ni < 8; ++ni)
#pragma unroll
      for (int rr = 0; rr < 4; ++rr)
        Es[(wv * 16 + lk * 4 + rr) * 136 + ni * 16 + lr] =
            f2bfu(fmaxf(a1[ni][rr] + fB1[128 + ni * 16 + lr], 0.f));   // Mid1
  }
  __syncthreads();
  for (int c = tid; c < 2048; c += 256) {   // stage W2a
    int r = c >> 4, k8 = c & 15;
    *reinterpret_cast<bf16x8*>(Wst + r * 136 + k8 * 8) =
        *reinterpret_cast<const bf16x8*>(W2T + (size_t)r * 256 + k8 * 8);
  }
  __syncthreads();
#pragma unroll
  for (int kt = 0; kt < 4; ++kt) {
    bf16x8 af = *reinterpret_cast<const bf16x8*>(Mid0 + (wv * 16 + lr) * 136 + kt * 32 + lk * 8);
#pragma unroll
    for (int ni = 0; ni < 8; ++ni) {
      bf16x8 bw = *reinterpret_cast<const bf16x8*>(Wst + (ni * 16 + lr) * 136 + kt * 32 + lk * 8);
      acc2[ni] = MFMA(af, bw, acc2[ni]);
    }
  }
  __syncthreads();
  for (int c = tid; c < 2048; c += 256) {   // stage W2b
    int r = c >> 4, k8 = c & 15;
    *reinterpret_cast<bf16x8*>(Wst + r * 136 + k8 * 8) =
        *reinterpret_cast<const bf16x8*>(W2T + (size_t)r * 256 + 128 + k8 * 8);
  }
  __syncthreads();
#pragma unroll
  for (int kt = 0; kt < 4; ++kt) {
    bf16x8 af = *reinterpret_cast<const bf16x8*>(Es + (wv * 16 + lr) * 136 + kt * 32 + lk * 8);
#pragma unroll
    for (int ni = 0; ni < 8; ++ni) {
      bf16x8 bw = *reinterpret_cast<const bf16x8*>(Wst + (ni * 16 + lr) * 136 + kt * 32 + lk * 8);
      acc2[ni] = MFMA(af, bw, acc2[ni]);
    }
  }
  __syncthreads();
  float* Tf = reinterpret_cast<float*>(Wst);
#pragma unroll
  for (int ni = 0; ni < 8; ++ni)
#pragma unroll
    for (int rr = 0; rr < 4; ++rr) {
      int row = wv * 16 + lk * 4 + rr;
      int col = ni * 16 + lr;
      Tf[row * 132 + col] = acc2[ni][rr] + fB2[col] + bf2f(rsv[ni][rr]);
    }
  __syncthreads();
  {
    int r = tid >> 2, jj = tid & 3;
    const float* tp = Tf + r * 132 + jj * 32;
    float s = 0.f;
    for (int c2 = 0; c2 < 32; ++c2) s += tp[c2];
    s += __shfl_xor(s, 1); s += __shfl_xor(s, 2);
    float mean = s * (1.f / 128.f);
    float v = 0.f;
    for (int c2 = 0; c2 < 32; ++c2) { float d = tp[c2] - mean; v += d * d; }
    v += __shfl_xor(v, 1); v += __shfl_xor(v, 2);
    if (jj == 0) { mu[r] = mean; rs[r] = 1.f / sqrtf(v * (1.f / 128.f) + 1e-5f); }
  }
  __syncthreads();
  for (int c = tid; c < 2048; c += 256) {
    int r = c >> 5, c4 = c & 31;
    int grow = m0 + r;
    if (grow >= M) continue;
    float4 t = ld4(Tf + r * 132 + c4 * 4);
    float4 gv = ld4(G2 + c4 * 4), bv = ld4(B2n + c4 * 4);
    float m = mu[r], ir = rs[r];
    u16x4 ub = { f2bfu(gv.x * (t.x - m) * ir + bv.x), f2bfu(gv.y * (t.y - m) * ir + bv.y),
                 f2bfu(gv.z * (t.z - m) * ir + bv.z), f2bfu(gv.w * (t.w - m) * ir + bv.w) };
    *reinterpret_cast<u16x4*>(Ebuf + (size_t)grow * 128 + c4 * 4) = ub;
  }
}

// ---------- CSR gather-reduce ----------
__global__ __launch_bounds__(256)
void reduce_k(const ushort_t* __restrict__ V, const float* __restrict__ wbuf,
              const int* __restrict__ start, const int2* __restrict__ csr_es,
              ushort_t* __restrict__ out)
{
  int t = blockIdx.x * 256 + threadIdx.x;
  int n = t >> 4;
  if (n >= NN) return;
  int j = t & 15;
  int p0 = start[n], p1 = start[n + 1];
  long long acc[8] = {};
  long long zacc = 0;
  for (int p = p0; p < p1; ++p) {
    int2 es = csr_es[p];
    float w = wbuf[(size_t)es.x * 8 + (j >> 1)];
    u16x8 vv = *reinterpret_cast<const u16x8*>(V + (size_t)es.y * 128 + j * 8);
    zacc += f2fx(w);
#pragma unroll
    for (int i = 0; i < 8; ++i) acc[i] += f2fx(bf2f(vv[i]) * w);
  }
  float zz = fx2f(zacc) + 1e-6f;
  u16x8 ob;
#pragma unroll
  for (int i = 0; i < 8; ++i) ob[i] = f2bfu(fx2f(acc[i]) / zz);
  *reinterpret_cast<u16x8*>(out + (size_t)n * 128 + j * 8) = ob;
}

// ---------- per-graph mean over 1000 nodes ----------
__global__ __launch_bounds__(256)
void graphmean_k(const float* __restrict__ h, float* __restrict__ hg)
{
  __shared__ float red[256];
  int g = blockIdx.x, tid = threadIdx.x;
  int c = tid & 127, half = tid >> 7;
  float s = 0.f;
  for (int r = half; r < 1000; r += 2) s += h[(size_t)(g * 1000 + r) * 128 + c];
  red[tid] = s;
  __syncthreads();
  if (half == 0) hg[g * 128 + c] = (red[c] + red[c + 128]) / 1000.0f;
}

// ---------- readout MLP: 128 -> 64 -> 32 -> 1 ----------
__global__ __launch_bounds__(256)
void readout_k(const float* __restrict__ hg,
               const float* __restrict__ w0, const float* __restrict__ b0,
               const float* __restrict__ w1, const float* __restrict__ b1,
               const float* __restrict__ w2, const float* __restrict__ b2,
               float* __restrict__ out)
{
  __shared__ float hs[25 * 128];
  __shared__ float t0[25 * 64];
  __shared__ float t1[25 * 32];
  int tid = threadIdx.x;
  for (int i = tid; i < 25 * 128; i += 256) hs[i] = hg[i];
  __syncthreads();
  for (int i = tid; i < 25 * 64; i += 256) {
    int r = i >> 6, c = i & 63;
    float a = b0[c];
    for (int k = 0; k < 128; k++) a += hs[r * 128 + k] * w0[k * 64 + c];
    t0[i] = fmaxf(a, 0.f);
  }
  __syncthreads();
  for (int i = tid; i < 25 * 32; i += 256) {
    int r = i >> 5, c = i & 31;
    float a = b1[c];
    for (int k = 0; k < 64; k++) a += t0[r * 64 + k] * w1[k * 32 + c];
    t1[i] = fmaxf(a, 0.f);
  }
  __syncthreads();
  if (tid < 25) {
    float a = b2[0];
    for (int k = 0; k < 32; k++) a += t1[tid * 32 + k] * w2[k];
    out[tid] = a;
  }
}

extern "C" void kernel_launch(void* const* d_in, const int* in_sizes, int n_in,
                              void* d_out, int out_size, void* d_ws, size_t ws_size,
                              hipStream_t stream)
{
  const float* emb_h  = (const float*)d_in[0];
  const float* emb_e  = (const float*)d_in[1];
  const float* w_qkve = (const float*)d_in[2];
  const float* o_w    = (const float*)d_in[3];
  const float* o_b    = (const float*)d_in[4];
  const float* ln_s   = (const float*)d_in[5];
  const float* ln_b   = (const float*)d_in[6];
  const float* ffn_w1 = (const float*)d_in[7];
  const float* ffn_b1 = (const float*)d_in[8];
  const float* ffn_w2 = (const float*)d_in[9];
  const float* ffn_b2 = (const float*)d_in[10];
  const float* mlp_w0 = (const float*)d_in[11];
  const float* mlp_b0 = (const float*)d_in[12];
  const float* mlp_w1 = (const float*)d_in[13];
  const float* mlp_b1 = (const float*)d_in[14];
  const float* mlp_w2 = (const float*)d_in[15];
  const float* mlp_b2 = (const float*)d_in[16];
  const int* tokens = (const int*)d_in[17];
  const int* etype  = (const int*)d_in[18];
  const int* src    = (const int*)d_in[19];
  const int* dst    = (const int*)d_in[20];

  // ---- workspace (~142 MB) ----
  char* ws = (char*)d_ws;
  size_t off = 0;
  auto alloc = [&](size_t bytes) { char* p = ws + off; off += bytes; return p; };
  int2*      csr_es = (int2*)alloc((size_t)NE * 8);
  float*     h      = (float*)alloc((size_t)NN * 128 * 4);
  float*     hg     = (float*)alloc(25 * 128 * 4);
  float*     wbuf   = (float*)alloc((size_t)NE * 8 * 4);
  int*       counts = (int*)alloc((size_t)NN * 4);
  int*       cursor = (int*)alloc((size_t)NN * 4);
  int*       startp = (int*)alloc((size_t)(NN + 1) * 4);
  ushort_t*  h_bf   = (ushort_t*)alloc((size_t)NN * 128 * 2);
  ushort_t*  ha_bf  = (ushort_t*)alloc((size_t)NN * 128 * 2);
  ushort_t*  Qb     = (ushort_t*)alloc((size_t)NN * 128 * 2);   // Q,K,V contiguous (osep)
  ushort_t*  Kb     = (ushort_t*)alloc((size_t)NN * 128 * 2);
  ushort_t*  Vb     = (ushort_t*)alloc((size_t)NN * 128 * 2);
  ushort_t*  e_bf   = (ushort_t*)alloc((size_t)NE * 128 * 2);
  ushort_t*  wt     = (ushort_t*)alloc(917504 * 2);

  ushort_t* qkveT = wt;            // 16 mats [128][128]
  ushort_t* owT   = wt + 262144;   // 8 mats  [128][128]
  ushort_t* w1T   = wt + 393216;   // 8 mats  [256][128]
  ushort_t* w2T   = wt + 655360;   // 8 mats  [128][256]
  wconv_k<<<1024, 256, 0, stream>>>(w_qkve, qkveT, 128, 128, 262144);
  wconv_k<<<512,  256, 0, stream>>>(o_w,    owT,   128, 128, 131072);
  wconv_k<<<1024, 256, 0, stream>>>(ffn_w1, w1T,   128, 256, 262144);
  wconv_k<<<1024, 256, 0, stream>>>(ffn_w2, w2T,   256, 128, 262144);

  gather_h_k<<<3125, 256, 0, stream>>>(emb_h, tokens, h, h_bf);
  gather_e_k<<<37500, 256, 0, stream>>>(emb_e, etype, e_bf);

  hipMemsetAsync(counts, 0, (size_t)NN * 4, stream);
  count_k<<<(NE + 255) / 256, 256, 0, stream>>>(dst, counts);
  scan_k<<<1, 1024, 0, stream>>>(counts, startp, cursor);
  scatter_k<<<(NE + 255) / 256, 256, 0, stream>>>(src, dst, cursor, csr_es);

  const int GN = (NN + 127) / 128;    // 196
  const int FN = (NN + 63) / 64;      // 391
  const int FE = (NE + 63) / 64;      // 4688

  for (int l = 0; l < 4; ++l) {
    const ushort_t* qkvT = qkveT + (size_t)l * 4 * 16384;
    const ushort_t* weT  = qkveT + ((size_t)l * 4 + 3) * 16384;
    const ushort_t* ow0T = owT + ((size_t)l * 2 + 0) * 16384;
    const ushort_t* ow1T = owT + ((size_t)l * 2 + 1) * 16384;
    const ushort_t* w1hT = w1T + ((size_t)l * 2 + 0) * 32768;
    const ushort_t* w1eT = w1T + ((size_t)l * 2 + 1) * 32768;
    const ushort_t* w2hT = w2T + ((size_t)l * 2 + 0) * 32768;
    const ushort_t* w2eT = w2T + ((size_t)l * 2 + 1) * 32768;
    const float* ob0 = o_b + ((size_t)l * 2 + 0) * 128;
    const float* ob1 = o_b + ((size_t)l * 2 + 1) * 128;
    const float* ls0 = ln_s + ((size_t)l * 4 + 0) * 128;
    const float* ls1 = ln_s + ((size_t)l * 4 + 1) * 128;
    const float* ls2 = ln_s + ((size_t)l * 4 + 2) * 128;
    const float* ls3 = ln_s + ((size_t)l * 4 + 3) * 128;
    const float* lb0 = ln_b + ((size_t)l * 4 + 0) * 128;
    const float* lb1 = ln_b + ((size_t)l * 4 + 1) * 128;
    const float* lb2 = ln_b + ((size_t)l * 4 + 2) * 128;
    const float* lb3 = ln_b + ((size_t)l * 4 + 3) * 128;
    const float* fb1h = ffn_b1 + ((size_t)l * 2 + 0) * 256;
    const float* fb1e = ffn_b1 + ((size_t)l * 2 + 1) * 256;
    const float* fb2h = ffn_b2 + ((size_t)l * 2 + 0) * 128;
    const float* fb2e = ffn_b2 + ((size_t)l * 2 + 1) * 128;

    // fused QKV projections
    gemmN_bf_k<<<dim3(GN, 3), 256, 0, stream>>>(h_bf, qkvT, 128, NN, 128,
        nullptr, 1, nullptr, nullptr, nullptr, nullptr, Qb, nullptr);

    // e-side mega kernel: pe -> score -> O_e+LN -> FFN+LN (in place on e_bf)
    efused_k<<<FE, 256, 0, stream>>>(e_bf, Qb, Kb, src, dst, wbuf,
        weT, ow1T, ob1, ls1, lb1, w1eT, fb1e, w2eT, fb2e, ls3, lb3, NE);

    // h-side attention + O_h + FFN
    reduce_k<<<1563, 256, 0, stream>>>(Vb, wbuf, startp, csr_es, ha_bf);
    gemmN_bf_k<<<dim3(GN, 1), 256, 0, stream>>>(ha_bf, ow0T, 128, NN, 128,
        ob0, 0, h, nullptr, ls0, lb0, h_bf, h);
    ffn_f_k<<<FN, 256, 0, stream>>>(h_bf, h, w1hT, fb1h, w2hT, fb2h,
                                    ls2, lb2, h_bf, h, NN);
  }

  graphmean_k<<<25, 256, 0, stream>>>(h, hg);
  readout_k<<<1, 256, 0, stream>>>(hg, mlp_w0, mlp_b0, mlp_w1, mlp_b1, mlp_w2, mlp_b2,
                                   (float*)d_out);
}